// Round 4
// baseline (6930.728 us; speedup 1.0000x reference)
//
#include <hip/hip_runtime.h>
#include <cmath>

// ---------------- problem constants ----------------
// T=32 B=32 H=W=84 C=3 HID=1024, conv: 84->42->21->11, CONV_OUT=3872
// outputs: logits[1024*7] | baseline[1024] | action[1024] | h_fin[65536] | c_fin[65536]
// activation layouts: conv1 out [n][42][42][32], conv2 out [n][21][21][32],
// conv3 out [n][11][11][32] (=[n][p][co], K-order p*32+co; fc_w1 repacked to match)

// ---------------- ws layout (floats) ----------------
// A      : 14,450,688  conv2 full [1024][21][21][32]; then FC partials @A+0 (8 x 1,048,576),
//                      fw1t @A+8388608 (3,964,928); then gx partials @A+{0,1}*4194304
// Bv     :  7,225,344  conv1 chunk [128][42][42][32]; later conv3out [1024][3872]
// fc1/cin/H0/H1: 1,048,576 each; cst 65,536; bsum 8,192; wt 19,296; sync 2 ints

__device__ __forceinline__ float eluf(float v) {
    return v > 0.f ? v : expm1f(v);
}

// generation-based grid barrier. All 512 blocks are co-resident (2/CU by LDS
// + launch_bounds). Device-scope fences handle cross-XCD L2 non-coherence.
// Replay-safe: works from any starting gen; cnt returns to 0 after each use.
__device__ __forceinline__ void gridbar(int* cnt, int* gen, int nb) {
    __syncthreads();
    if (threadIdx.x == 0) {
        int g = __hip_atomic_load(gen, __ATOMIC_RELAXED, __HIP_MEMORY_SCOPE_AGENT);
        __threadfence();   // release this block's Hout/cst stores (L2 wb)
        int v = __hip_atomic_fetch_add(cnt, 1, __ATOMIC_ACQ_REL, __HIP_MEMORY_SCOPE_AGENT);
        if (v == nb - 1) {
            __hip_atomic_store(cnt, 0, __ATOMIC_RELAXED, __HIP_MEMORY_SCOPE_AGENT);
            __hip_atomic_fetch_add(gen, 1, __ATOMIC_RELEASE, __HIP_MEMORY_SCOPE_AGENT);
        } else {
            int spins = 0;
            while (__hip_atomic_load(gen, __ATOMIC_ACQUIRE, __HIP_MEMORY_SCOPE_AGENT) == g &&
                   ++spins < (1 << 22))
                __builtin_amdgcn_s_sleep(10);
        }
        __threadfence();   // acquire other blocks' stores (L2 inv)
    }
    __syncthreads();
}

// weights repacked k-major: wt[(tap*CI+ci)*32 + co]
__global__ __launch_bounds__(256) void repack_w(const float* __restrict__ w1,
    const float* __restrict__ w2, const float* __restrict__ w3, float* __restrict__ wt)
{
    int i = blockIdx.x * 256 + threadIdx.x;
    if (i < 864) {
        int co = i & 31, r = i >> 5;
        int tap = r / 3, ci = r - tap * 3;
        int k1 = tap / 3, k2 = tap - k1 * 3;
        wt[i] = w1[co * 27 + ci * 9 + k1 * 3 + k2];
    } else if (i < 10080) {
        int o = i - 864;
        int co = o & 31, r = o >> 5;
        int tap = r >> 5, ci = r & 31;
        int k1 = tap / 3, k2 = tap - k1 * 3;
        wt[i] = w2[co * 288 + ci * 9 + k1 * 3 + k2];
    } else if (i < 19296) {
        int o = i - 10080;
        int co = o & 31, r = o >> 5;
        int tap = r >> 5, ci = r & 31;
        int k1 = tap / 3, k2 = tap - k1 * 3;
        wt[i] = w3[co * 288 + ci * 9 + k1 * 3 + k2];
    }
}

__global__ __launch_bounds__(256) void bsum_k(const float* __restrict__ bih0,
    const float* __restrict__ bhh0, const float* __restrict__ bih1,
    const float* __restrict__ bhh1, float* __restrict__ bsum, int* __restrict__ sync)
{
    int i = blockIdx.x * 256 + threadIdx.x;
    if (i == 0) { sync[0] = 0; sync[1] = 0; }
    if (i < 4096) bsum[i] = bih0[i] + bhh0[i];
    else if (i < 8192) bsum[i] = bih1[i - 4096] + bhh1[i - 4096];
}

// conv1: frame [n][h][w][3] -> out [nl][ox][oy][32], 42x42, stride2 pad1, ELU
__global__ __launch_bounds__(256) void conv1_k(const float* __restrict__ frame,
    const float* __restrict__ w1t, const float* __restrict__ b1,
    float* __restrict__ out, int n0)
{
    __shared__ float As[27][132];
    __shared__ float Bs[27][32];
    int tid = threadIdx.x;
    if (tid < 216) ((float4*)Bs)[tid] = ((const float4*)w1t)[tid];

    int p0 = blockIdx.x << 7;
    int pxl = tid & 127;
    int half = tid >> 7;
    {
        int p = p0 + pxl;
        int nl = p / 1764;
        int rem = p - nl * 1764;
        int ox = rem / 42;
        int oy = rem - ox * 42;
        const float* fr = frame + (size_t)(n0 + nl) * 21168;
        for (int tap = half; tap < 9; tap += 2) {
            int k1 = tap / 3, k2 = tap - k1 * 3;
            int u = 2 * ox - 1 + k1;
            int v = 2 * oy - 1 + k2;
            bool ok = (u >= 0) && (u < 84) && (v >= 0) && (v < 84);
            int uc = ok ? u : 0, vc = ok ? v : 0;
            const float* fp = fr + (vc * 84 + uc) * 3;
            float x0 = fp[0], x1 = fp[1], x2 = fp[2];
            if (!ok) { x0 = 0.f; x1 = 0.f; x2 = 0.f; }
            As[tap * 3 + 0][pxl] = x0;
            As[tap * 3 + 1][pxl] = x1;
            As[tap * 3 + 2][pxl] = x2;
        }
    }
    __syncthreads();

    int tx = tid & 7, ty = tid >> 3;
    float acc[4][4];
#pragma unroll
    for (int i = 0; i < 4; i++)
#pragma unroll
        for (int j = 0; j < 4; j++) acc[i][j] = 0.f;

#pragma unroll 9
    for (int k = 0; k < 27; k++) {
        float4 a = *(const float4*)&As[k][ty << 2];
        float4 b = *(const float4*)&Bs[k][tx << 2];
        acc[0][0] = fmaf(a.x, b.x, acc[0][0]); acc[0][1] = fmaf(a.x, b.y, acc[0][1]);
        acc[0][2] = fmaf(a.x, b.z, acc[0][2]); acc[0][3] = fmaf(a.x, b.w, acc[0][3]);
        acc[1][0] = fmaf(a.y, b.x, acc[1][0]); acc[1][1] = fmaf(a.y, b.y, acc[1][1]);
        acc[1][2] = fmaf(a.y, b.z, acc[1][2]); acc[1][3] = fmaf(a.y, b.w, acc[1][3]);
        acc[2][0] = fmaf(a.z, b.x, acc[2][0]); acc[2][1] = fmaf(a.z, b.y, acc[2][1]);
        acc[2][2] = fmaf(a.z, b.z, acc[2][2]); acc[2][3] = fmaf(a.z, b.w, acc[2][3]);
        acc[3][0] = fmaf(a.w, b.x, acc[3][0]); acc[3][1] = fmaf(a.w, b.y, acc[3][1]);
        acc[3][2] = fmaf(a.w, b.z, acc[3][2]); acc[3][3] = fmaf(a.w, b.w, acc[3][3]);
    }

    float4 bc = *(const float4*)(b1 + (tx << 2));
#pragma unroll
    for (int i = 0; i < 4; i++) {
        float4 o;
        o.x = eluf(acc[i][0] + bc.x);
        o.y = eluf(acc[i][1] + bc.y);
        o.z = eluf(acc[i][2] + bc.z);
        o.w = eluf(acc[i][3] + bc.w);
        *(float4*)(out + (size_t)(p0 + (ty << 2) + i) * 32 + (tx << 2)) = o;
    }
}

// conv2/conv3: in [n][IS][IS][32] -> out [n+off][OS][OS][32], stride2 pad1, ELU
template<int IS, int OS>
__global__ __launch_bounds__(256) void convg_k(const float* __restrict__ in,
    const float* __restrict__ wtb, const float* __restrict__ bias,
    float* __restrict__ out, int pOff)
{
    __shared__ float Bs[288 * 32];
    __shared__ float As[32][132];
    int tid = threadIdx.x;
    {
        const float4* src = (const float4*)wtb;
        float4* dst = (float4*)Bs;
#pragma unroll
        for (int r = 0; r < 9; r++) dst[tid + r * 256] = src[tid + r * 256];
    }
    const int OS2 = OS * OS;
    int p0 = blockIdx.x << 7;
    int c4 = tid & 7;
    int pn[4], pox[4], poy[4];
#pragma unroll
    for (int i = 0; i < 4; i++) {
        int px = (tid >> 3) + (i << 5);
        int p = p0 + px;
        int n = p / OS2;
        int rem = p - n * OS2;
        int ox = rem / OS;
        pn[i] = n; pox[i] = ox; poy[i] = rem - ox * OS;
    }

    int tx = tid & 7, ty = tid >> 3;
    float acc[4][4];
#pragma unroll
    for (int i = 0; i < 4; i++)
#pragma unroll
        for (int j = 0; j < 4; j++) acc[i][j] = 0.f;

    for (int k1 = 0; k1 < 3; k1++) {
        for (int k2 = 0; k2 < 3; k2++) {
            __syncthreads();
#pragma unroll
            for (int i = 0; i < 4; i++) {
                int px = (tid >> 3) + (i << 5);
                int u = 2 * pox[i] - 1 + k1;
                int v = 2 * poy[i] - 1 + k2;
                bool ok = (u >= 0) && (u < IS) && (v >= 0) && (v < IS);
                int uc = ok ? u : 0, vc = ok ? v : 0;
                float4 val = *(const float4*)(in +
                    ((size_t)((pn[i] * IS + uc) * IS + vc)) * 32 + (c4 << 2));
                if (!ok) { val.x = 0.f; val.y = 0.f; val.z = 0.f; val.w = 0.f; }
                As[(c4 << 2) + 0][px] = val.x;
                As[(c4 << 2) + 1][px] = val.y;
                As[(c4 << 2) + 2][px] = val.z;
                As[(c4 << 2) + 3][px] = val.w;
            }
            __syncthreads();
            const float* bsrc = Bs + (size_t)((k1 * 3 + k2) << 5) * 32;
#pragma unroll 8
            for (int k = 0; k < 32; k++) {
                float4 a = *(const float4*)&As[k][ty << 2];
                float4 b = *(const float4*)&bsrc[(k << 5) + (tx << 2)];
                acc[0][0] = fmaf(a.x, b.x, acc[0][0]); acc[0][1] = fmaf(a.x, b.y, acc[0][1]);
                acc[0][2] = fmaf(a.x, b.z, acc[0][2]); acc[0][3] = fmaf(a.x, b.w, acc[0][3]);
                acc[1][0] = fmaf(a.y, b.x, acc[1][0]); acc[1][1] = fmaf(a.y, b.y, acc[1][1]);
                acc[1][2] = fmaf(a.y, b.z, acc[1][2]); acc[1][3] = fmaf(a.y, b.w, acc[1][3]);
                acc[2][0] = fmaf(a.z, b.x, acc[2][0]); acc[2][1] = fmaf(a.z, b.y, acc[2][1]);
                acc[2][2] = fmaf(a.z, b.z, acc[2][2]); acc[2][3] = fmaf(a.z, b.w, acc[2][3]);
                acc[3][0] = fmaf(a.w, b.x, acc[3][0]); acc[3][1] = fmaf(a.w, b.y, acc[3][1]);
                acc[3][2] = fmaf(a.w, b.z, acc[3][2]); acc[3][3] = fmaf(a.w, b.w, acc[3][3]);
            }
        }
    }

    float4 bc = *(const float4*)(bias + (tx << 2));
#pragma unroll
    for (int i = 0; i < 4; i++) {
        float4 o;
        o.x = eluf(acc[i][0] + bc.x);
        o.y = eluf(acc[i][1] + bc.y);
        o.z = eluf(acc[i][2] + bc.z);
        o.w = eluf(acc[i][3] + bc.w);
        *(float4*)(out + (size_t)(pOff + p0 + (ty << 2) + i) * 32 + (tx << 2)) = o;
    }
}

// fw1t[h][p*32+co] = fw1[h][co*121+p]  (match conv3 K-order)
__global__ __launch_bounds__(256) void repack_fw1(const float* __restrict__ fw1,
    float* __restrict__ fw1t)
{
    __shared__ float row[3872];
    int h = blockIdx.x;
    const float* src = fw1 + (size_t)h * 3872;
    for (int j = threadIdx.x; j < 3872; j += 256) row[j] = src[j];
    __syncthreads();
    float* dst = fw1t + (size_t)h * 3872;
    for (int j = threadIdx.x; j < 3872; j += 256) {
        int p = j >> 5, co = j & 31;
        dst[j] = row[co * 121 + p];
    }
}

// C[m,n] = sum_k A[m*K+k] * Bm[n*K+k] over this z's K-chunk.
// 128x128 tile, 8x8/thread, dbuf LDS. Partial output per z.
// NOTE: plain __launch_bounds__(256). (256,3) made the allocator cap at 84 VGPR
// and spill the 64-reg accumulator to scratch: FETCH 24MB->2GB, 167->1280us.
__global__ __launch_bounds__(256) void gemm128(const float* __restrict__ A,
    const float* __restrict__ Bm, float* __restrict__ Cbase, size_t Cstride,
    int N, int K, int Nt, int kchunk)
{
    __shared__ float As[2][16][132];
    __shared__ float Bs[2][16][132];
    int tid = threadIdx.x;
    int bid = blockIdx.x;
    int nt = bid % Nt, mt = bid / Nt;
    int n0 = nt << 7, m0 = mt << 7;
    int kbeg = blockIdx.z * kchunk;
    int kend = kbeg + kchunk;
    if (kend > K) kend = K;
    int T = (kend - kbeg) >> 4;
    float* C = Cbase + (size_t)blockIdx.z * Cstride;

    int tx = tid & 15, ty = tid >> 4;
    int r0 = tid >> 2, kc0 = (tid & 3) << 2;
    int r1 = (tid + 256) >> 2, kc1 = kc0;
    const float* a0p = A + (size_t)(m0 + r0) * K + kbeg + kc0;
    const float* a1p = A + (size_t)(m0 + r1) * K + kbeg + kc1;
    const float* b0p = Bm + (size_t)(n0 + r0) * K + kbeg + kc0;
    const float* b1p = Bm + (size_t)(n0 + r1) * K + kbeg + kc1;

    float acc[8][8];
#pragma unroll
    for (int i = 0; i < 8; i++)
#pragma unroll
        for (int j = 0; j < 8; j++) acc[i][j] = 0.f;

    float4 pa0 = *(const float4*)a0p;
    float4 pa1 = *(const float4*)a1p;
    float4 pb0 = *(const float4*)b0p;
    float4 pb1 = *(const float4*)b1p;
    As[0][kc0 + 0][r0] = pa0.x; As[0][kc0 + 1][r0] = pa0.y;
    As[0][kc0 + 2][r0] = pa0.z; As[0][kc0 + 3][r0] = pa0.w;
    As[0][kc1 + 0][r1] = pa1.x; As[0][kc1 + 1][r1] = pa1.y;
    As[0][kc1 + 2][r1] = pa1.z; As[0][kc1 + 3][r1] = pa1.w;
    Bs[0][kc0 + 0][r0] = pb0.x; Bs[0][kc0 + 1][r0] = pb0.y;
    Bs[0][kc0 + 2][r0] = pb0.z; Bs[0][kc0 + 3][r0] = pb0.w;
    Bs[0][kc1 + 0][r1] = pb1.x; Bs[0][kc1 + 1][r1] = pb1.y;
    Bs[0][kc1 + 2][r1] = pb1.z; Bs[0][kc1 + 3][r1] = pb1.w;

    int p = 0;
    for (int t = 0; t < T; t++) {
        __syncthreads();
        bool more = (t + 1 < T);
        if (more) {
            int ko = (t + 1) << 4;
            pa0 = *(const float4*)(a0p + ko);
            pa1 = *(const float4*)(a1p + ko);
            pb0 = *(const float4*)(b0p + ko);
            pb1 = *(const float4*)(b1p + ko);
        }
#pragma unroll
        for (int k = 0; k < 16; k++) {
            float a[8], b[8];
            *(float4*)&a[0] = *(const float4*)&As[p][k][ty << 2];
            *(float4*)&a[4] = *(const float4*)&As[p][k][64 + (ty << 2)];
            *(float4*)&b[0] = *(const float4*)&Bs[p][k][tx << 2];
            *(float4*)&b[4] = *(const float4*)&Bs[p][k][64 + (tx << 2)];
#pragma unroll
            for (int i = 0; i < 8; i++)
#pragma unroll
                for (int j = 0; j < 8; j++) acc[i][j] = fmaf(a[i], b[j], acc[i][j]);
        }
        if (more) {
            int q = p ^ 1;
            As[q][kc0 + 0][r0] = pa0.x; As[q][kc0 + 1][r0] = pa0.y;
            As[q][kc0 + 2][r0] = pa0.z; As[q][kc0 + 3][r0] = pa0.w;
            As[q][kc1 + 0][r1] = pa1.x; As[q][kc1 + 1][r1] = pa1.y;
            As[q][kc1 + 2][r1] = pa1.z; As[q][kc1 + 3][r1] = pa1.w;
            Bs[q][kc0 + 0][r0] = pb0.x; Bs[q][kc0 + 1][r0] = pb0.y;
            Bs[q][kc0 + 2][r0] = pb0.z; Bs[q][kc0 + 3][r0] = pb0.w;
            Bs[q][kc1 + 0][r1] = pb1.x; Bs[q][kc1 + 1][r1] = pb1.y;
            Bs[q][kc1 + 2][r1] = pb1.z; Bs[q][kc1 + 3][r1] = pb1.w;
            p = q;
        }
    }

#pragma unroll
    for (int i = 0; i < 8; i++) {
        int row = m0 + ((i < 4) ? ((ty << 2) + i) : (64 + (ty << 2) + i - 4));
        float* cp0 = C + (size_t)row * N + n0 + (tx << 2);
        float4 s0; s0.x = acc[i][0]; s0.y = acc[i][1]; s0.z = acc[i][2]; s0.w = acc[i][3];
        float4 s1; s1.x = acc[i][4]; s1.y = acc[i][5]; s1.z = acc[i][6]; s1.w = acc[i][7];
        *(float4*)cp0 = s0;
        *(float4*)(cp0 + 64) = s1;
    }
}

// out[i] = relu(bias[i%1024] + sum_z p[i + z*stride]) over 1048576 elements
__global__ __launch_bounds__(256) void bias_relu_sum(const float* __restrict__ p,
    size_t stride, int nz, const float* __restrict__ b, float* __restrict__ out)
{
    int i = blockIdx.x * 256 + threadIdx.x;
    float v = b[i & 1023];
    for (int z = 0; z < nz; z++) v += p[i + (size_t)z * stride];
    out[i] = v > 0.f ? v : 0.f;
}

// PERSISTENT per-layer LSTM: one launch runs all 32 time steps, separated by
// grid barriers. 512 blocks x 256 thr, 2 units/block, 2 blocks/CU (LDS 69.6KB).
// whh rows for both units live in LDS for the WHOLE layer (staged once).
// h chunks (128 cols) double-buffered with register prefetch: 8 barriers/step.
// thread: bl=tid&31 (batch), s=(tid>>5)&3 (k-slice, 32 cols/chunk), u=tid>>7 (unit).
__global__ __launch_bounds__(256, 2) void lstm_layer(
    const float* __restrict__ gxa, const float* __restrict__ gxb,
    const float* __restrict__ whh,   // [4*1024][1024] layer weights
    const float* __restrict__ bsum,  // [4096] layer slice
    const float* __restrict__ h0i,   // [32][1024] initial h (layer slice)
    const float* __restrict__ c0i,   // [32][1024] initial c (layer slice)
    float* __restrict__ cstate,      // [32][1024] running c (layer slice)
    float* __restrict__ Hout,        // [32][32][1024] layer outputs
    const unsigned char* __restrict__ done8,
    int* __restrict__ cnt, int* __restrict__ gen)
{
    __shared__ float Ws[2][4][1024];       // 32 KB: both units' gate rows
    __shared__ float Hs[2][32][132];       // 33.8 KB: dbuf h chunk
    __shared__ float part[2][3][32][4];    // 3 KB
    const int tid = threadIdx.x;
    const int bl  = tid & 31;
    const int s   = (tid >> 5) & 3;
    const int u   = tid >> 7;
    const int jb  = (int)blockIdx.x << 1;
    const int jj  = jb + u;
    const int r0  = tid >> 5;              // staging rows r0 + 8*rep
    const int c4s = tid & 31;

    // stage both units' weights once: 2048 float4, 8/thread, coalesced
#pragma unroll
    for (int rep = 0; rep < 8; rep++) {
        int id = tid + (rep << 8);
        int uu = id >> 10, g = (id >> 8) & 3, c4 = id & 255;
        *(float4*)&Ws[uu][g][c4 << 2] =
            *(const float4*)(whh + ((size_t)g * 1024 + (jb + uu)) * 1024 + (c4 << 2));
    }
    __syncthreads();

    for (int t = 0; t < 32; t++) {
        const float* hp = t ? (Hout + (size_t)(t - 1) * 32768) : h0i;
        const unsigned char* dm = done8 + (t << 5);
        float nds[4];
#pragma unroll
        for (int rep = 0; rep < 4; rep++) nds[rep] = dm[r0 + (rep << 3)] ? 0.f : 1.f;

        // early-issue tail inputs (only s==0 threads consume them)
        float gv0 = 0, gv1 = 0, gv2 = 0, gv3 = 0, bv0 = 0, bv1 = 0, bv2 = 0, bv3 = 0;
        if (!s) {
            int row = (t << 5) + bl;
            const float* gpa = gxa + (size_t)row * 4096 + jj;
            const float* gpb = gxb + (size_t)row * 4096 + jj;
            gv0 = gpa[0]    + gpb[0];    gv1 = gpa[1024] + gpb[1024];
            gv2 = gpa[2048] + gpb[2048]; gv3 = gpa[3072] + gpb[3072];
            bv0 = bsum[jj];        bv1 = bsum[jj + 1024];
            bv2 = bsum[jj + 2048]; bv3 = bsum[jj + 3072];
        }

        // prologue: stage masked h chunk 0
#pragma unroll
        for (int rep = 0; rep < 4; rep++) {
            int r = r0 + (rep << 3);
            float4 h4 = *(const float4*)(hp + (size_t)r * 1024 + (c4s << 2));
            float nd = nds[rep];
            h4.x *= nd; h4.y *= nd; h4.z *= nd; h4.w *= nd;
            *(float4*)&Hs[0][r][c4s << 2] = h4;
        }

        float a0 = 0.f, a1 = 0.f, a2 = 0.f, a3 = 0.f;
        int p = 0;
        for (int kt = 0; kt < 8; kt++) {
            __syncthreads();
            float4 pre[4];
            bool more = (kt < 7);
            if (more) {
                int ko = (kt + 1) << 7;
#pragma unroll
                for (int rep = 0; rep < 4; rep++) {
                    int r = r0 + (rep << 3);
                    pre[rep] = *(const float4*)(hp + (size_t)r * 1024 + ko + (c4s << 2));
                }
            }
#pragma unroll
            for (int q = 0; q < 8; q++) {
                int kl = (s << 5) + (q << 2);
                float4 h4 = *(const float4*)&Hs[p][bl][kl];
                int kG = (kt << 7) + kl;
                float4 w0 = *(const float4*)&Ws[u][0][kG];
                float4 w1 = *(const float4*)&Ws[u][1][kG];
                float4 w2 = *(const float4*)&Ws[u][2][kG];
                float4 w3 = *(const float4*)&Ws[u][3][kG];
                a0 = fmaf(h4.x, w0.x, fmaf(h4.y, w0.y, fmaf(h4.z, w0.z, fmaf(h4.w, w0.w, a0))));
                a1 = fmaf(h4.x, w1.x, fmaf(h4.y, w1.y, fmaf(h4.z, w1.z, fmaf(h4.w, w1.w, a1))));
                a2 = fmaf(h4.x, w2.x, fmaf(h4.y, w2.y, fmaf(h4.z, w2.z, fmaf(h4.w, w2.w, a2))));
                a3 = fmaf(h4.x, w3.x, fmaf(h4.y, w3.y, fmaf(h4.z, w3.z, fmaf(h4.w, w3.w, a3))));
            }
            if (more) {
                int q2 = p ^ 1;
#pragma unroll
                for (int rep = 0; rep < 4; rep++) {
                    int r = r0 + (rep << 3);
                    float nd = nds[rep];
                    float4 h4 = pre[rep];
                    h4.x *= nd; h4.y *= nd; h4.z *= nd; h4.w *= nd;
                    *(float4*)&Hs[q2][r][c4s << 2] = h4;
                }
                p = q2;
            }
        }

        if (s) {
            float4 pv; pv.x = a0; pv.y = a1; pv.z = a2; pv.w = a3;
            *(float4*)&part[u][s - 1][bl][0] = pv;
        }
        __syncthreads();
        if (!s) {
#pragma unroll
            for (int r = 0; r < 3; r++) {
                float4 pv = *(const float4*)&part[u][r][bl][0];
                a0 += pv.x; a1 += pv.y; a2 += pv.z; a3 += pv.w;
            }
            float g0 = a0 + gv0 + bv0;
            float g1 = a1 + gv1 + bv1;
            float g2 = a2 + gv2 + bv2;
            float g3 = a3 + gv3 + bv3;
            size_t cidx = (size_t)bl * 1024 + jj;
            float nd = dm[bl] ? 0.f : 1.f;
            float cpv = (t ? cstate[cidx] : c0i[cidx]) * nd;
            float si = 1.f / (1.f + expf(-g0));
            float sf = 1.f / (1.f + expf(-g1));
            float so = 1.f / (1.f + expf(-g3));
            float cn = sf * cpv + si * tanhf(g2);
            float hn = so * tanhf(cn);
            cstate[cidx] = cn;
            Hout[(size_t)((t << 5) + bl) * 1024 + jj] = hn;
        }
        if (t < 31) gridbar(cnt, gen, (int)gridDim.x);
    }
}

__global__ __launch_bounds__(256) void heads_k(const float* __restrict__ Hc,
    const float* __restrict__ pw, const float* __restrict__ pb,
    const float* __restrict__ bw, const float* __restrict__ bbias,
    float* __restrict__ out)
{
    __shared__ float red[8][264];
    int n = blockIdx.x, tid = threadIdx.x;
    float4 x4 = *(const float4*)(Hc + (size_t)n * 1024 + (tid << 2));
#pragma unroll
    for (int a = 0; a < 7; a++) {
        float4 w4 = *(const float4*)(pw + (size_t)a * 1024 + (tid << 2));
        red[a][tid] = x4.x * w4.x + x4.y * w4.y + x4.z * w4.z + x4.w * w4.w;
    }
    {
        float4 w4 = *(const float4*)(bw + (tid << 2));
        red[7][tid] = x4.x * w4.x + x4.y * w4.y + x4.z * w4.z + x4.w * w4.w;
    }
    __syncthreads();
    for (int off = 128; off > 0; off >>= 1) {
        if (tid < off) {
#pragma unroll
            for (int a = 0; a < 8; a++) red[a][tid] += red[a][tid + off];
        }
        __syncthreads();
    }
    if (tid == 0) {
        float best = -1e30f; int bi = 0;
        for (int a = 0; a < 7; a++) {
            float L = red[a][0] + pb[a];
            out[n * 7 + a] = L;
            if (L > best) { best = L; bi = a; }
        }
        out[7168 + n] = red[7][0] + bbias[0];
        out[8192 + n] = (float)bi;
    }
}

__global__ __launch_bounds__(256) void final_copy(const float* __restrict__ H0,
    const float* __restrict__ H1, const float* __restrict__ cst, float* __restrict__ out)
{
    int i = blockIdx.x * 256 + threadIdx.x;   // 131072 exact
    if (i < 65536) {
        int l = i >> 15;
        int rem = i & 32767;
        const float* H = l ? H1 : H0;
        out[9216 + i] = H[(size_t)(31 * 32) * 1024 + rem];
    } else {
        out[74752 + (i - 65536)] = cst[i - 65536];
    }
}

extern "C" void kernel_launch(void* const* d_in, const int* in_sizes, int n_in,
                              void* d_out, int out_size, void* d_ws, size_t ws_size,
                              hipStream_t stream)
{
    (void)in_sizes; (void)n_in; (void)out_size; (void)ws_size;
    const float* frame = (const float*)d_in[0];
    const unsigned char* done8 = (const unsigned char*)d_in[1];
    const float* h0   = (const float*)d_in[2];
    const float* c0   = (const float*)d_in[3];
    const float* cw1  = (const float*)d_in[4];
    const float* cb1  = (const float*)d_in[5];
    const float* cw2  = (const float*)d_in[6];
    const float* cb2  = (const float*)d_in[7];
    const float* cw3  = (const float*)d_in[8];
    const float* cb3  = (const float*)d_in[9];
    const float* fw1  = (const float*)d_in[10];
    const float* fb1  = (const float*)d_in[11];
    const float* fw2  = (const float*)d_in[12];
    const float* fb2  = (const float*)d_in[13];
    const float* wih0 = (const float*)d_in[14];
    const float* whh0 = (const float*)d_in[15];
    const float* bih0 = (const float*)d_in[16];
    const float* bhh0 = (const float*)d_in[17];
    const float* wih1 = (const float*)d_in[18];
    const float* whh1 = (const float*)d_in[19];
    const float* bih1 = (const float*)d_in[20];
    const float* bhh1 = (const float*)d_in[21];
    const float* pw   = (const float*)d_in[22];
    const float* pb   = (const float*)d_in[23];
    const float* bw   = (const float*)d_in[24];
    const float* bbias= (const float*)d_in[25];

    float* ws   = (float*)d_ws;
    float* A    = ws;                      // 14,450,688
    float* Bv   = A + 14450688;            //  7,225,344
    float* fc1  = Bv + 7225344;            //  1,048,576
    float* cin  = fc1 + 1048576;           //  1,048,576
    float* H0   = cin + 1048576;           //  1,048,576
    float* H1   = H0 + 1048576;            //  1,048,576
    float* cst  = H1 + 1048576;            //     65,536
    float* bsum = cst + 65536;             //      8,192
    float* wt   = bsum + 8192;             //     19,296
    int*   syncI = (int*)(wt + 19296);     //      2 ints (grid barrier cnt/gen)
    float* fw1t = A + 8388608;             //  3,964,928 (after FC1 partials)
    float* fcp  = A;                       //  FC partials: up to 8 x 1,048,576 (ends at fw1t)
    float* gxp  = A;                       //  gx partials: 2 x 4,194,304 (after fw1t dead)
    float* conv2f = A;
    float* conv3o = Bv;
    float* out = (float*)d_out;

    repack_w<<<76, 256, 0, stream>>>(cw1, cw2, cw3, wt);
    bsum_k<<<32, 256, 0, stream>>>(bih0, bhh0, bih1, bhh1, bsum, syncI);

    for (int ch = 0; ch < 8; ch++) {
        conv1_k<<<1764, 256, 0, stream>>>(frame, wt, cb1, Bv, ch * 128);
        convg_k<42, 21><<<441, 256, 0, stream>>>(Bv, wt + 864, cb2, conv2f, ch * 128 * 441);
    }
    convg_k<21, 11><<<968, 256, 0, stream>>>(conv2f, wt + 10080, cb3, conv3o, 0);
    repack_fw1<<<1024, 256, 0, stream>>>(fw1, fw1t);

    // FC1: M=1024 N=1024 K=3872, Nt=8, splitk 8 (kchunk 496; last chunk 400) -> 512 blocks
    { dim3 g(64, 1, 8); gemm128<<<g, 256, 0, stream>>>(conv3o, fw1t, fcp, 1048576, 1024, 3872, 8, 496); }
    bias_relu_sum<<<4096, 256, 0, stream>>>(fcp, 1048576, 8, fb1, fc1);
    // FC2: K=1024, splitk 8 (kchunk 128) -> 512 blocks
    { dim3 g(64, 1, 8); gemm128<<<g, 256, 0, stream>>>(fc1, fw2, fcp, 1048576, 1024, 1024, 8, 128); }
    bias_relu_sum<<<4096, 256, 0, stream>>>(fcp, 1048576, 8, fb2, cin);

    // gx0: M=1024 N=4096 K=1024, Nt=32, splitk 2 -> 512 blocks (fw1t dead now)
    { dim3 g(256, 1, 2); gemm128<<<g, 256, 0, stream>>>(cin, wih0, gxp, 4194304, 4096, 1024, 32, 512); }
    // layer 0: persistent, 32 steps, grid barriers between steps
    lstm_layer<<<512, 256, 0, stream>>>(gxp, gxp + 4194304, whh0, bsum,
                                        h0, c0, cst, H0, done8, syncI, syncI + 1);
    // gx1 reuses gx0 partial slots (dead after layer-0)
    { dim3 g(256, 1, 2); gemm128<<<g, 256, 0, stream>>>(H0, wih1, gxp, 4194304, 4096, 1024, 32, 512); }
    // layer 1
    lstm_layer<<<512, 256, 0, stream>>>(gxp, gxp + 4194304, whh1, bsum + 4096,
                                        h0 + 32768, c0 + 32768, cst + 32768, H1, done8, syncI, syncI + 1);

    heads_k<<<1024, 256, 0, stream>>>(H1, pw, pb, bw, bbias, out);
    final_copy<<<512, 256, 0, stream>>>(H0, H1, cst, out);
}

// Round 5
// 1886.386 us; speedup vs baseline: 3.6741x; 3.6741x over previous
//
#include <hip/hip_runtime.h>
#include <cmath>

// ---------------- problem constants ----------------
// T=32 B=32 H=W=84 C=3 HID=1024, conv: 84->42->21->11, CONV_OUT=3872
// outputs: logits[1024*7] | baseline[1024] | action[1024] | h_fin[65536] | c_fin[65536]
// activation layouts: conv1 out [n][42][42][32], conv2 out [n][21][21][32],
// conv3 out [n][11][11][32] (=[n][p][co], K-order p*32+co; fc_w1 repacked to match)

// ---------------- ws layout (floats) ----------------
// A      : 14,450,688  conv2 full [1024][21][21][32]; then FC partials @A+0 (8 x 1,048,576),
//                      fw1t @A+8388608 (3,964,928); then gx partials @A+{0,1}*4194304
// Bv     :  7,225,344  conv1 chunk [128][42][42][32]; later conv3out [1024][3872]
// fc1/cin/H0/H1: 1,048,576 each; cst 65,536; bsum 8,192; wt 19,296

__device__ __forceinline__ float eluf(float v) {
    return v > 0.f ? v : expm1f(v);
}

// weights repacked k-major: wt[(tap*CI+ci)*32 + co]
__global__ __launch_bounds__(256) void repack_w(const float* __restrict__ w1,
    const float* __restrict__ w2, const float* __restrict__ w3, float* __restrict__ wt)
{
    int i = blockIdx.x * 256 + threadIdx.x;
    if (i < 864) {
        int co = i & 31, r = i >> 5;
        int tap = r / 3, ci = r - tap * 3;
        int k1 = tap / 3, k2 = tap - k1 * 3;
        wt[i] = w1[co * 27 + ci * 9 + k1 * 3 + k2];
    } else if (i < 10080) {
        int o = i - 864;
        int co = o & 31, r = o >> 5;
        int tap = r >> 5, ci = r & 31;
        int k1 = tap / 3, k2 = tap - k1 * 3;
        wt[i] = w2[co * 288 + ci * 9 + k1 * 3 + k2];
    } else if (i < 19296) {
        int o = i - 10080;
        int co = o & 31, r = o >> 5;
        int tap = r >> 5, ci = r & 31;
        int k1 = tap / 3, k2 = tap - k1 * 3;
        wt[i] = w3[co * 288 + ci * 9 + k1 * 3 + k2];
    }
}

__global__ __launch_bounds__(256) void bsum_k(const float* __restrict__ bih0,
    const float* __restrict__ bhh0, const float* __restrict__ bih1,
    const float* __restrict__ bhh1, float* __restrict__ bsum)
{
    int i = blockIdx.x * 256 + threadIdx.x;
    if (i < 4096) bsum[i] = bih0[i] + bhh0[i];
    else if (i < 8192) bsum[i] = bih1[i - 4096] + bhh1[i - 4096];
}

// conv1: frame [n][h][w][3] -> out [nl][ox][oy][32], 42x42, stride2 pad1, ELU
__global__ __launch_bounds__(256) void conv1_k(const float* __restrict__ frame,
    const float* __restrict__ w1t, const float* __restrict__ b1,
    float* __restrict__ out, int n0)
{
    __shared__ float As[27][132];
    __shared__ float Bs[27][32];
    int tid = threadIdx.x;
    if (tid < 216) ((float4*)Bs)[tid] = ((const float4*)w1t)[tid];

    int p0 = blockIdx.x << 7;
    int pxl = tid & 127;
    int half = tid >> 7;
    {
        int p = p0 + pxl;
        int nl = p / 1764;
        int rem = p - nl * 1764;
        int ox = rem / 42;
        int oy = rem - ox * 42;
        const float* fr = frame + (size_t)(n0 + nl) * 21168;
        for (int tap = half; tap < 9; tap += 2) {
            int k1 = tap / 3, k2 = tap - k1 * 3;
            int u = 2 * ox - 1 + k1;
            int v = 2 * oy - 1 + k2;
            bool ok = (u >= 0) && (u < 84) && (v >= 0) && (v < 84);
            int uc = ok ? u : 0, vc = ok ? v : 0;
            const float* fp = fr + (vc * 84 + uc) * 3;
            float x0 = fp[0], x1 = fp[1], x2 = fp[2];
            if (!ok) { x0 = 0.f; x1 = 0.f; x2 = 0.f; }
            As[tap * 3 + 0][pxl] = x0;
            As[tap * 3 + 1][pxl] = x1;
            As[tap * 3 + 2][pxl] = x2;
        }
    }
    __syncthreads();

    int tx = tid & 7, ty = tid >> 3;
    float acc[4][4];
#pragma unroll
    for (int i = 0; i < 4; i++)
#pragma unroll
        for (int j = 0; j < 4; j++) acc[i][j] = 0.f;

#pragma unroll 9
    for (int k = 0; k < 27; k++) {
        float4 a = *(const float4*)&As[k][ty << 2];
        float4 b = *(const float4*)&Bs[k][tx << 2];
        acc[0][0] = fmaf(a.x, b.x, acc[0][0]); acc[0][1] = fmaf(a.x, b.y, acc[0][1]);
        acc[0][2] = fmaf(a.x, b.z, acc[0][2]); acc[0][3] = fmaf(a.x, b.w, acc[0][3]);
        acc[1][0] = fmaf(a.y, b.x, acc[1][0]); acc[1][1] = fmaf(a.y, b.y, acc[1][1]);
        acc[1][2] = fmaf(a.y, b.z, acc[1][2]); acc[1][3] = fmaf(a.y, b.w, acc[1][3]);
        acc[2][0] = fmaf(a.z, b.x, acc[2][0]); acc[2][1] = fmaf(a.z, b.y, acc[2][1]);
        acc[2][2] = fmaf(a.z, b.z, acc[2][2]); acc[2][3] = fmaf(a.z, b.w, acc[2][3]);
        acc[3][0] = fmaf(a.w, b.x, acc[3][0]); acc[3][1] = fmaf(a.w, b.y, acc[3][1]);
        acc[3][2] = fmaf(a.w, b.z, acc[3][2]); acc[3][3] = fmaf(a.w, b.w, acc[3][3]);
    }

    float4 bc = *(const float4*)(b1 + (tx << 2));
#pragma unroll
    for (int i = 0; i < 4; i++) {
        float4 o;
        o.x = eluf(acc[i][0] + bc.x);
        o.y = eluf(acc[i][1] + bc.y);
        o.z = eluf(acc[i][2] + bc.z);
        o.w = eluf(acc[i][3] + bc.w);
        *(float4*)(out + (size_t)(p0 + (ty << 2) + i) * 32 + (tx << 2)) = o;
    }
}

// conv2/conv3: in [n][IS][IS][32] -> out [n+off][OS][OS][32], stride2 pad1, ELU
template<int IS, int OS>
__global__ __launch_bounds__(256) void convg_k(const float* __restrict__ in,
    const float* __restrict__ wtb, const float* __restrict__ bias,
    float* __restrict__ out, int pOff)
{
    __shared__ float Bs[288 * 32];
    __shared__ float As[32][132];
    int tid = threadIdx.x;
    {
        const float4* src = (const float4*)wtb;
        float4* dst = (float4*)Bs;
#pragma unroll
        for (int r = 0; r < 9; r++) dst[tid + r * 256] = src[tid + r * 256];
    }
    const int OS2 = OS * OS;
    int p0 = blockIdx.x << 7;
    int c4 = tid & 7;
    int pn[4], pox[4], poy[4];
#pragma unroll
    for (int i = 0; i < 4; i++) {
        int px = (tid >> 3) + (i << 5);
        int p = p0 + px;
        int n = p / OS2;
        int rem = p - n * OS2;
        int ox = rem / OS;
        pn[i] = n; pox[i] = ox; poy[i] = rem - ox * OS;
    }

    int tx = tid & 7, ty = tid >> 3;
    float acc[4][4];
#pragma unroll
    for (int i = 0; i < 4; i++)
#pragma unroll
        for (int j = 0; j < 4; j++) acc[i][j] = 0.f;

    for (int k1 = 0; k1 < 3; k1++) {
        for (int k2 = 0; k2 < 3; k2++) {
            __syncthreads();
#pragma unroll
            for (int i = 0; i < 4; i++) {
                int px = (tid >> 3) + (i << 5);
                int u = 2 * pox[i] - 1 + k1;
                int v = 2 * poy[i] - 1 + k2;
                bool ok = (u >= 0) && (u < IS) && (v >= 0) && (v < IS);
                int uc = ok ? u : 0, vc = ok ? v : 0;
                float4 val = *(const float4*)(in +
                    ((size_t)((pn[i] * IS + uc) * IS + vc)) * 32 + (c4 << 2));
                if (!ok) { val.x = 0.f; val.y = 0.f; val.z = 0.f; val.w = 0.f; }
                As[(c4 << 2) + 0][px] = val.x;
                As[(c4 << 2) + 1][px] = val.y;
                As[(c4 << 2) + 2][px] = val.z;
                As[(c4 << 2) + 3][px] = val.w;
            }
            __syncthreads();
            const float* bsrc = Bs + (size_t)((k1 * 3 + k2) << 5) * 32;
#pragma unroll 8
            for (int k = 0; k < 32; k++) {
                float4 a = *(const float4*)&As[k][ty << 2];
                float4 b = *(const float4*)&bsrc[(k << 5) + (tx << 2)];
                acc[0][0] = fmaf(a.x, b.x, acc[0][0]); acc[0][1] = fmaf(a.x, b.y, acc[0][1]);
                acc[0][2] = fmaf(a.x, b.z, acc[0][2]); acc[0][3] = fmaf(a.x, b.w, acc[0][3]);
                acc[1][0] = fmaf(a.y, b.x, acc[1][0]); acc[1][1] = fmaf(a.y, b.y, acc[1][1]);
                acc[1][2] = fmaf(a.y, b.z, acc[1][2]); acc[1][3] = fmaf(a.y, b.w, acc[1][3]);
                acc[2][0] = fmaf(a.z, b.x, acc[2][0]); acc[2][1] = fmaf(a.z, b.y, acc[2][1]);
                acc[2][2] = fmaf(a.z, b.z, acc[2][2]); acc[2][3] = fmaf(a.z, b.w, acc[2][3]);
                acc[3][0] = fmaf(a.w, b.x, acc[3][0]); acc[3][1] = fmaf(a.w, b.y, acc[3][1]);
                acc[3][2] = fmaf(a.w, b.z, acc[3][2]); acc[3][3] = fmaf(a.w, b.w, acc[3][3]);
            }
        }
    }

    float4 bc = *(const float4*)(bias + (tx << 2));
#pragma unroll
    for (int i = 0; i < 4; i++) {
        float4 o;
        o.x = eluf(acc[i][0] + bc.x);
        o.y = eluf(acc[i][1] + bc.y);
        o.z = eluf(acc[i][2] + bc.z);
        o.w = eluf(acc[i][3] + bc.w);
        *(float4*)(out + (size_t)(pOff + p0 + (ty << 2) + i) * 32 + (tx << 2)) = o;
    }
}

// fw1t[h][p*32+co] = fw1[h][co*121+p]  (match conv3 K-order)
__global__ __launch_bounds__(256) void repack_fw1(const float* __restrict__ fw1,
    float* __restrict__ fw1t)
{
    __shared__ float row[3872];
    int h = blockIdx.x;
    const float* src = fw1 + (size_t)h * 3872;
    for (int j = threadIdx.x; j < 3872; j += 256) row[j] = src[j];
    __syncthreads();
    float* dst = fw1t + (size_t)h * 3872;
    for (int j = threadIdx.x; j < 3872; j += 256) {
        int p = j >> 5, co = j & 31;
        dst[j] = row[co * 121 + p];
    }
}

// C[m,n] = sum_k A[m*K+k] * Bm[n*K+k] over this z's K-chunk.
// 128x128 tile, 8x8/thread, dbuf LDS. Partial output per z.
// NOTE: plain __launch_bounds__(256). (256,3) made the allocator cap at 84 VGPR
// and spill the 64-reg accumulator to scratch: FETCH 24MB->2GB, 167->1280us.
__global__ __launch_bounds__(256) void gemm128(const float* __restrict__ A,
    const float* __restrict__ Bm, float* __restrict__ Cbase, size_t Cstride,
    int N, int K, int Nt, int kchunk)
{
    __shared__ float As[2][16][132];
    __shared__ float Bs[2][16][132];
    int tid = threadIdx.x;
    int bid = blockIdx.x;
    int nt = bid % Nt, mt = bid / Nt;
    int n0 = nt << 7, m0 = mt << 7;
    int kbeg = blockIdx.z * kchunk;
    int kend = kbeg + kchunk;
    if (kend > K) kend = K;
    int T = (kend - kbeg) >> 4;
    float* C = Cbase + (size_t)blockIdx.z * Cstride;

    int tx = tid & 15, ty = tid >> 4;
    int r0 = tid >> 2, kc0 = (tid & 3) << 2;
    int r1 = (tid + 256) >> 2, kc1 = kc0;
    const float* a0p = A + (size_t)(m0 + r0) * K + kbeg + kc0;
    const float* a1p = A + (size_t)(m0 + r1) * K + kbeg + kc1;
    const float* b0p = Bm + (size_t)(n0 + r0) * K + kbeg + kc0;
    const float* b1p = Bm + (size_t)(n0 + r1) * K + kbeg + kc1;

    float acc[8][8];
#pragma unroll
    for (int i = 0; i < 8; i++)
#pragma unroll
        for (int j = 0; j < 8; j++) acc[i][j] = 0.f;

    float4 pa0 = *(const float4*)a0p;
    float4 pa1 = *(const float4*)a1p;
    float4 pb0 = *(const float4*)b0p;
    float4 pb1 = *(const float4*)b1p;
    As[0][kc0 + 0][r0] = pa0.x; As[0][kc0 + 1][r0] = pa0.y;
    As[0][kc0 + 2][r0] = pa0.z; As[0][kc0 + 3][r0] = pa0.w;
    As[0][kc1 + 0][r1] = pa1.x; As[0][kc1 + 1][r1] = pa1.y;
    As[0][kc1 + 2][r1] = pa1.z; As[0][kc1 + 3][r1] = pa1.w;
    Bs[0][kc0 + 0][r0] = pb0.x; Bs[0][kc0 + 1][r0] = pb0.y;
    Bs[0][kc0 + 2][r0] = pb0.z; Bs[0][kc0 + 3][r0] = pb0.w;
    Bs[0][kc1 + 0][r1] = pb1.x; Bs[0][kc1 + 1][r1] = pb1.y;
    Bs[0][kc1 + 2][r1] = pb1.z; Bs[0][kc1 + 3][r1] = pb1.w;

    int p = 0;
    for (int t = 0; t < T; t++) {
        __syncthreads();
        bool more = (t + 1 < T);
        if (more) {
            int ko = (t + 1) << 4;
            pa0 = *(const float4*)(a0p + ko);
            pa1 = *(const float4*)(a1p + ko);
            pb0 = *(const float4*)(b0p + ko);
            pb1 = *(const float4*)(b1p + ko);
        }
#pragma unroll
        for (int k = 0; k < 16; k++) {
            float a[8], b[8];
            *(float4*)&a[0] = *(const float4*)&As[p][k][ty << 2];
            *(float4*)&a[4] = *(const float4*)&As[p][k][64 + (ty << 2)];
            *(float4*)&b[0] = *(const float4*)&Bs[p][k][tx << 2];
            *(float4*)&b[4] = *(const float4*)&Bs[p][k][64 + (tx << 2)];
#pragma unroll
            for (int i = 0; i < 8; i++)
#pragma unroll
                for (int j = 0; j < 8; j++) acc[i][j] = fmaf(a[i], b[j], acc[i][j]);
        }
        if (more) {
            int q = p ^ 1;
            As[q][kc0 + 0][r0] = pa0.x; As[q][kc0 + 1][r0] = pa0.y;
            As[q][kc0 + 2][r0] = pa0.z; As[q][kc0 + 3][r0] = pa0.w;
            As[q][kc1 + 0][r1] = pa1.x; As[q][kc1 + 1][r1] = pa1.y;
            As[q][kc1 + 2][r1] = pa1.z; As[q][kc1 + 3][r1] = pa1.w;
            Bs[q][kc0 + 0][r0] = pb0.x; Bs[q][kc0 + 1][r0] = pb0.y;
            Bs[q][kc0 + 2][r0] = pb0.z; Bs[q][kc0 + 3][r0] = pb0.w;
            Bs[q][kc1 + 0][r1] = pb1.x; Bs[q][kc1 + 1][r1] = pb1.y;
            Bs[q][kc1 + 2][r1] = pb1.z; Bs[q][kc1 + 3][r1] = pb1.w;
            p = q;
        }
    }

#pragma unroll
    for (int i = 0; i < 8; i++) {
        int row = m0 + ((i < 4) ? ((ty << 2) + i) : (64 + (ty << 2) + i - 4));
        float* cp0 = C + (size_t)row * N + n0 + (tx << 2);
        float4 s0; s0.x = acc[i][0]; s0.y = acc[i][1]; s0.z = acc[i][2]; s0.w = acc[i][3];
        float4 s1; s1.x = acc[i][4]; s1.y = acc[i][5]; s1.z = acc[i][6]; s1.w = acc[i][7];
        *(float4*)cp0 = s0;
        *(float4*)(cp0 + 64) = s1;
    }
}

// out[i] = relu(bias[i%1024] + sum_z p[i + z*stride]) over 1048576 elements
__global__ __launch_bounds__(256) void bias_relu_sum(const float* __restrict__ p,
    size_t stride, int nz, const float* __restrict__ b, float* __restrict__ out)
{
    int i = blockIdx.x * 256 + threadIdx.x;
    float v = b[i & 1023];
    for (int z = 0; z < nz; z++) v += p[i + (size_t)z * stride];
    out[i] = v > 0.f ? v : 0.f;
}

// one LSTM step for one layer. grid 512 blocks = 512 unit-PAIRS (2 units/block,
// halves the per-step h broadcast vs 1 unit/block). Register-tiled matvec:
// thread = 4 batches x 1 unit x 4 gates over a 64-col k-slice -> LDS bytes/FMA
// drops 5 -> 2 (r3's lstm_step was LDS-read-BW bound at ~9.7us/step).
// thread: bg=tid&7 (4 batches bg*4..+3), u=(tid>>3)&1 (unit), s=tid>>4 (k-slice).
// h tile XOR-swizzled (col4 ^= bg-of-row) to break the 4-way bank conflict of
// the 132-float row stride. 16 k-slice partials reduced via padded part[16][65].
__global__ __launch_bounds__(256) void lstm_step(
    const float* __restrict__ gxa,     // partial [1024][4096] rows t*32+b
    const float* __restrict__ gxb,     // partial
    const float* __restrict__ whh,     // [4096][1024]
    const float* __restrict__ bsum,    // [4096] (caller offsets for layer)
    const float* __restrict__ hprev,   // rows b*1024 (pre-offset for t/layer)
    const float* __restrict__ cprev,   // idx b*1024+j (pre-offset for layer)
    float* __restrict__ cout,          // idx b*1024+j
    float* __restrict__ Hout,          // rows t*32+b
    const unsigned char* __restrict__ dmask, // &done[t*32]
    int t)
{
    __shared__ float Hs[32][132];      // h chunk: 32 batches x 128 cols (swizzled)
    __shared__ float Ws[8][132];       // w chunk: 2 units x 4 gates x 128 cols
    __shared__ float4 part[16][65];    // k-slice partials, odd stride (bank spread)
    int tid = threadIdx.x;
    int bg = tid & 7;                  // batch group (rows bg*4 .. bg*4+3)
    int u  = (tid >> 3) & 1;           // unit within pair
    int s  = tid >> 4;                 // 0..15 k-slice (8 cols per 128-chunk)
    int jb = (int)blockIdx.x << 1;
    int r0 = tid >> 5;                 // staging row base (rows r0+8*rep)
    int c40 = tid & 31;                // staging col4

    float nds[4];
#pragma unroll
    for (int rep = 0; rep < 4; rep++) nds[rep] = dmask[r0 + (rep << 3)] ? 0.f : 1.f;

    // weight staging map: uu=tid>>7, g=(tid>>5)&3, wc=tid&31 (1 float4/thread)
    int wuu = tid >> 7, wg = (tid >> 5) & 3, wc = tid & 31;
    const float* wsrc = whh + ((size_t)(wg << 10) + jb + wuu) * 1024 + (wc << 2);

    float acc[4][4];
#pragma unroll
    for (int i = 0; i < 4; i++)
#pragma unroll
        for (int g = 0; g < 4; g++) acc[i][g] = 0.f;

    for (int kt = 0; kt < 8; kt++) {
        if (kt) __syncthreads();
        // stage h[32 rows][128 cols], masked + swizzled: 1024 float4, 4/thread
#pragma unroll
        for (int rep = 0; rep < 4; rep++) {
            int r = r0 + (rep << 3);
            float4 h4 = *(const float4*)(hprev + (size_t)r * 1024 + (kt << 7) + (c40 << 2));
            float nd = nds[rep];
            h4.x *= nd; h4.y *= nd; h4.z *= nd; h4.w *= nd;
            *(float4*)&Hs[r][(c40 ^ ((r >> 2) & 7)) << 2] = h4;
        }
        // stage w[2 units][4 gates][128 cols]: 256 float4, 1/thread, coalesced
        *(float4*)&Ws[(wuu << 2) + wg][wc << 2] = *(const float4*)(wsrc + (kt << 7));
        __syncthreads();
        // slice s covers col4 {2s, 2s+1} of this chunk
#pragma unroll
        for (int kq = 0; kq < 2; kq++) {
            int col4 = (s << 1) + kq;
            float4 w0 = *(const float4*)&Ws[(u << 2) + 0][col4 << 2];
            float4 w1 = *(const float4*)&Ws[(u << 2) + 1][col4 << 2];
            float4 w2 = *(const float4*)&Ws[(u << 2) + 2][col4 << 2];
            float4 w3 = *(const float4*)&Ws[(u << 2) + 3][col4 << 2];
#pragma unroll
            for (int i = 0; i < 4; i++) {
                float4 h4 = *(const float4*)&Hs[(bg << 2) + i][(col4 ^ bg) << 2];
                acc[i][0] = fmaf(h4.x, w0.x, fmaf(h4.y, w0.y, fmaf(h4.z, w0.z, fmaf(h4.w, w0.w, acc[i][0]))));
                acc[i][1] = fmaf(h4.x, w1.x, fmaf(h4.y, w1.y, fmaf(h4.z, w1.z, fmaf(h4.w, w1.w, acc[i][1]))));
                acc[i][2] = fmaf(h4.x, w2.x, fmaf(h4.y, w2.y, fmaf(h4.z, w2.z, fmaf(h4.w, w2.w, acc[i][2]))));
                acc[i][3] = fmaf(h4.x, w3.x, fmaf(h4.y, w3.y, fmaf(h4.z, w3.z, fmaf(h4.w, w3.w, acc[i][3]))));
            }
        }
    }

    // all 256 threads write their 4-batch x 4-gate partial (one float4 per batch)
#pragma unroll
    for (int i = 0; i < 4; i++) {
        float4 pv; pv.x = acc[i][0]; pv.y = acc[i][1]; pv.z = acc[i][2]; pv.w = acc[i][3];
        part[s][(((bg << 2) + i) << 1) + u] = pv;
    }
    __syncthreads();
    // 64 finishers: (b, u) sums 16 slices, applies gx/bias + gate math
    if (tid < 64) {
        int b = tid & 31, uu = tid >> 5;
        float4 sum; sum.x = 0.f; sum.y = 0.f; sum.z = 0.f; sum.w = 0.f;
#pragma unroll
        for (int sl = 0; sl < 16; sl++) {
            float4 pv = part[sl][(b << 1) + uu];
            sum.x += pv.x; sum.y += pv.y; sum.z += pv.z; sum.w += pv.w;
        }
        int j = jb + uu;
        int row = (t << 5) + b;
        const float* gpa = gxa + (size_t)row * 4096 + j;
        const float* gpb = gxb + (size_t)row * 4096 + j;
        float g0 = sum.x + gpa[0]    + gpb[0]    + bsum[j];
        float g1 = sum.y + gpa[1024] + gpb[1024] + bsum[j + 1024];
        float g2 = sum.z + gpa[2048] + gpb[2048] + bsum[j + 2048];
        float g3 = sum.w + gpa[3072] + gpb[3072] + bsum[j + 3072];
        float nd = dmask[b] ? 0.f : 1.f;
        float cp = cprev[(size_t)b * 1024 + j] * nd;
        float si = 1.f / (1.f + expf(-g0));
        float sf = 1.f / (1.f + expf(-g1));
        float so = 1.f / (1.f + expf(-g3));
        float cn = sf * cp + si * tanhf(g2);
        float hn = so * tanhf(cn);
        cout[(size_t)b * 1024 + j] = cn;
        Hout[(size_t)row * 1024 + j] = hn;
    }
}

__global__ __launch_bounds__(256) void heads_k(const float* __restrict__ Hc,
    const float* __restrict__ pw, const float* __restrict__ pb,
    const float* __restrict__ bw, const float* __restrict__ bbias,
    float* __restrict__ out)
{
    __shared__ float red[8][264];
    int n = blockIdx.x, tid = threadIdx.x;
    float4 x4 = *(const float4*)(Hc + (size_t)n * 1024 + (tid << 2));
#pragma unroll
    for (int a = 0; a < 7; a++) {
        float4 w4 = *(const float4*)(pw + (size_t)a * 1024 + (tid << 2));
        red[a][tid] = x4.x * w4.x + x4.y * w4.y + x4.z * w4.z + x4.w * w4.w;
    }
    {
        float4 w4 = *(const float4*)(bw + (tid << 2));
        red[7][tid] = x4.x * w4.x + x4.y * w4.y + x4.z * w4.z + x4.w * w4.w;
    }
    __syncthreads();
    for (int off = 128; off > 0; off >>= 1) {
        if (tid < off) {
#pragma unroll
            for (int a = 0; a < 8; a++) red[a][tid] += red[a][tid + off];
        }
        __syncthreads();
    }
    if (tid == 0) {
        float best = -1e30f; int bi = 0;
        for (int a = 0; a < 7; a++) {
            float L = red[a][0] + pb[a];
            out[n * 7 + a] = L;
            if (L > best) { best = L; bi = a; }
        }
        out[7168 + n] = red[7][0] + bbias[0];
        out[8192 + n] = (float)bi;
    }
}

__global__ __launch_bounds__(256) void final_copy(const float* __restrict__ H0,
    const float* __restrict__ H1, const float* __restrict__ cst, float* __restrict__ out)
{
    int i = blockIdx.x * 256 + threadIdx.x;   // 131072 exact
    if (i < 65536) {
        int l = i >> 15;
        int rem = i & 32767;
        const float* H = l ? H1 : H0;
        out[9216 + i] = H[(size_t)(31 * 32) * 1024 + rem];
    } else {
        out[74752 + (i - 65536)] = cst[i - 65536];
    }
}

extern "C" void kernel_launch(void* const* d_in, const int* in_sizes, int n_in,
                              void* d_out, int out_size, void* d_ws, size_t ws_size,
                              hipStream_t stream)
{
    (void)in_sizes; (void)n_in; (void)out_size; (void)ws_size;
    const float* frame = (const float*)d_in[0];
    const unsigned char* done8 = (const unsigned char*)d_in[1];
    const float* h0   = (const float*)d_in[2];
    const float* c0   = (const float*)d_in[3];
    const float* cw1  = (const float*)d_in[4];
    const float* cb1  = (const float*)d_in[5];
    const float* cw2  = (const float*)d_in[6];
    const float* cb2  = (const float*)d_in[7];
    const float* cw3  = (const float*)d_in[8];
    const float* cb3  = (const float*)d_in[9];
    const float* fw1  = (const float*)d_in[10];
    const float* fb1  = (const float*)d_in[11];
    const float* fw2  = (const float*)d_in[12];
    const float* fb2  = (const float*)d_in[13];
    const float* wih0 = (const float*)d_in[14];
    const float* whh0 = (const float*)d_in[15];
    const float* bih0 = (const float*)d_in[16];
    const float* bhh0 = (const float*)d_in[17];
    const float* wih1 = (const float*)d_in[18];
    const float* whh1 = (const float*)d_in[19];
    const float* bih1 = (const float*)d_in[20];
    const float* bhh1 = (const float*)d_in[21];
    const float* pw   = (const float*)d_in[22];
    const float* pb   = (const float*)d_in[23];
    const float* bw   = (const float*)d_in[24];
    const float* bbias= (const float*)d_in[25];

    float* ws   = (float*)d_ws;
    float* A    = ws;                      // 14,450,688
    float* Bv   = A + 14450688;            //  7,225,344
    float* fc1  = Bv + 7225344;            //  1,048,576
    float* cin  = fc1 + 1048576;           //  1,048,576
    float* H0   = cin + 1048576;           //  1,048,576
    float* H1   = H0 + 1048576;            //  1,048,576
    float* cst  = H1 + 1048576;            //     65,536
    float* bsum = cst + 65536;             //      8,192
    float* wt   = bsum + 8192;             //     19,296
    float* fw1t = A + 8388608;             //  3,964,928 (after FC1 partials)
    float* fcp  = A;                       //  FC partials: up to 8 x 1,048,576 (ends at fw1t)
    float* gxp  = A;                       //  gx partials: 2 x 4,194,304 (after fw1t dead)
    float* conv2f = A;
    float* conv3o = Bv;
    float* out = (float*)d_out;

    repack_w<<<76, 256, 0, stream>>>(cw1, cw2, cw3, wt);
    bsum_k<<<32, 256, 0, stream>>>(bih0, bhh0, bih1, bhh1, bsum);

    for (int ch = 0; ch < 8; ch++) {
        conv1_k<<<1764, 256, 0, stream>>>(frame, wt, cb1, Bv, ch * 128);
        convg_k<42, 21><<<441, 256, 0, stream>>>(Bv, wt + 864, cb2, conv2f, ch * 128 * 441);
    }
    convg_k<21, 11><<<968, 256, 0, stream>>>(conv2f, wt + 10080, cb3, conv3o, 0);
    repack_fw1<<<1024, 256, 0, stream>>>(fw1, fw1t);

    // FC1: M=1024 N=1024 K=3872, Nt=8, splitk 8 (kchunk 496; last chunk 400) -> 512 blocks
    { dim3 g(64, 1, 8); gemm128<<<g, 256, 0, stream>>>(conv3o, fw1t, fcp, 1048576, 1024, 3872, 8, 496); }
    bias_relu_sum<<<4096, 256, 0, stream>>>(fcp, 1048576, 8, fb1, fc1);
    // FC2: K=1024, splitk 8 (kchunk 128) -> 512 blocks
    { dim3 g(64, 1, 8); gemm128<<<g, 256, 0, stream>>>(fc1, fw2, fcp, 1048576, 1024, 1024, 8, 128); }
    bias_relu_sum<<<4096, 256, 0, stream>>>(fcp, 1048576, 8, fb2, cin);

    // gx0: M=1024 N=4096 K=1024, Nt=32, splitk 2 -> 512 blocks (fw1t dead now)
    { dim3 g(256, 1, 2); gemm128<<<g, 256, 0, stream>>>(cin, wih0, gxp, 4194304, 4096, 1024, 32, 512); }
    for (int t = 0; t < 32; t++) {
        const float* hp = t ? (H0 + (size_t)(t - 1) * 32768) : h0;
        const float* cp = t ? cst : c0;
        lstm_step<<<512, 256, 0, stream>>>(gxp, gxp + 4194304, whh0, bsum, hp, cp, cst, H0, done8 + t * 32, t);
    }
    // gx1 reuses gx0 partial slots (dead after layer-0 steps)
    { dim3 g(256, 1, 2); gemm128<<<g, 256, 0, stream>>>(H0, wih1, gxp, 4194304, 4096, 1024, 32, 512); }
    for (int t = 0; t < 32; t++) {
        const float* hp = t ? (H1 + (size_t)(t - 1) * 32768) : (h0 + 32768);
        const float* cp = t ? (cst + 32768) : (c0 + 32768);
        lstm_step<<<512, 256, 0, stream>>>(gxp, gxp + 4194304, whh1, bsum + 4096, hp, cp, cst + 32768, H1, done8 + t * 32, t);
    }
    heads_k<<<1024, 256, 0, stream>>>(H1, pw, pb, bw, bbias, out);
    final_copy<<<512, 256, 0, stream>>>(H0, H1, cst, out);
}

// Round 6
// 1703.666 us; speedup vs baseline: 4.0681x; 1.1073x over previous
//
#include <hip/hip_runtime.h>
#include <cmath>

// ---------------- problem constants ----------------
// T=32 B=32 H=W=84 C=3 HID=1024, conv: 84->42->21->11, CONV_OUT=3872
// outputs: logits[1024*7] | baseline[1024] | action[1024] | h_fin[65536] | c_fin[65536]
// GEMMs now split-bf16 MFMA (hi+lo planes, 3 mfma passes ~ fp32 precision).

// ---------------- ws layout (floats) ----------------
// A (14,450,688): conv2f full; then {c3hi,c3lo,f1hi,f1lo} bf16 for FC1;
//   then FC2 partials (4x1,048,576); then {w0hi,w0lo,w1hi,w1lo}@0..8,388,608
//   + gx fp32 [1024][4096] @8,388,608..12,582,912
// Bv (7,225,344): conv1 chunk; conv3o fp32; FC1 partials (6x1,048,576);
//   then {fc1hi,fc1lo,fw2hi,fw2lo,cinhi,cinlo,h0hi,h0lo} bf16
// fc1/cin/H0/H1: 1,048,576 each; cst 65,536; bsum 8,192; wt 19,296

typedef short bf16x8 __attribute__((ext_vector_type(8)));
typedef float f32x4 __attribute__((ext_vector_type(4)));

__device__ __forceinline__ float eluf(float v) {
    return v > 0.f ? v : expm1f(v);
}

// round-to-nearest-even fp32 -> bf16 bits
__device__ __forceinline__ unsigned short f2bf(float x) {
    unsigned int u = __float_as_uint(x);
    u += 0x7FFFu + ((u >> 16) & 1u);
    return (unsigned short)(u >> 16);
}

// split x into hi + lo bf16 planes (x ~= hi + lo, error ~2^-17 rel)
__device__ __forceinline__ void bfsplit(float x, unsigned short& h, unsigned short& l) {
    unsigned short hb = f2bf(x);
    float hf = __uint_as_float((unsigned int)hb << 16);
    h = hb;
    l = f2bf(x - hf);
}

// weights repacked k-major: wt[(tap*CI+ci)*32 + co]
__global__ __launch_bounds__(256) void repack_w(const float* __restrict__ w1,
    const float* __restrict__ w2, const float* __restrict__ w3, float* __restrict__ wt)
{
    int i = blockIdx.x * 256 + threadIdx.x;
    if (i < 864) {
        int co = i & 31, r = i >> 5;
        int tap = r / 3, ci = r - tap * 3;
        int k1 = tap / 3, k2 = tap - k1 * 3;
        wt[i] = w1[co * 27 + ci * 9 + k1 * 3 + k2];
    } else if (i < 10080) {
        int o = i - 864;
        int co = o & 31, r = o >> 5;
        int tap = r >> 5, ci = r & 31;
        int k1 = tap / 3, k2 = tap - k1 * 3;
        wt[i] = w2[co * 288 + ci * 9 + k1 * 3 + k2];
    } else if (i < 19296) {
        int o = i - 10080;
        int co = o & 31, r = o >> 5;
        int tap = r >> 5, ci = r & 31;
        int k1 = tap / 3, k2 = tap - k1 * 3;
        wt[i] = w3[co * 288 + ci * 9 + k1 * 3 + k2];
    }
}

__global__ __launch_bounds__(256) void bsum_k(const float* __restrict__ bih0,
    const float* __restrict__ bhh0, const float* __restrict__ bih1,
    const float* __restrict__ bhh1, float* __restrict__ bsum)
{
    int i = blockIdx.x * 256 + threadIdx.x;
    if (i < 4096) bsum[i] = bih0[i] + bhh0[i];
    else if (i < 8192) bsum[i] = bih1[i - 4096] + bhh1[i - 4096];
}

// elementwise fp32 -> bf16 hi/lo planes, 8 elems/thread, exact grids
__global__ __launch_bounds__(256) void cvt_split(const float* __restrict__ src,
    unsigned short* __restrict__ hi, unsigned short* __restrict__ lo, int n)
{
    int i = (blockIdx.x * 256 + threadIdx.x) << 3;
    if (i >= n) return;
    float4 v0 = *(const float4*)(src + i);
    float4 v1 = *(const float4*)(src + i + 4);
    float vs[8] = {v0.x, v0.y, v0.z, v0.w, v1.x, v1.y, v1.z, v1.w};
    bf16x8 hv, lv;
#pragma unroll
    for (int j = 0; j < 8; j++) {
        unsigned short hb, lb;
        bfsplit(vs[j], hb, lb);
        hv[j] = (short)hb;
        lv[j] = (short)lb;
    }
    *(bf16x8*)(hi + i) = hv;
    *(bf16x8*)(lo + i) = lv;
}

// conv1: frame [n][h][w][3] -> out [nl][ox][oy][32], 42x42, stride2 pad1, ELU
__global__ __launch_bounds__(256) void conv1_k(const float* __restrict__ frame,
    const float* __restrict__ w1t, const float* __restrict__ b1,
    float* __restrict__ out, int n0)
{
    __shared__ float As[27][132];
    __shared__ float Bs[27][32];
    int tid = threadIdx.x;
    if (tid < 216) ((float4*)Bs)[tid] = ((const float4*)w1t)[tid];

    int p0 = blockIdx.x << 7;
    int pxl = tid & 127;
    int half = tid >> 7;
    {
        int p = p0 + pxl;
        int nl = p / 1764;
        int rem = p - nl * 1764;
        int ox = rem / 42;
        int oy = rem - ox * 42;
        const float* fr = frame + (size_t)(n0 + nl) * 21168;
        for (int tap = half; tap < 9; tap += 2) {
            int k1 = tap / 3, k2 = tap - k1 * 3;
            int u = 2 * ox - 1 + k1;
            int v = 2 * oy - 1 + k2;
            bool ok = (u >= 0) && (u < 84) && (v >= 0) && (v < 84);
            int uc = ok ? u : 0, vc = ok ? v : 0;
            const float* fp = fr + (vc * 84 + uc) * 3;
            float x0 = fp[0], x1 = fp[1], x2 = fp[2];
            if (!ok) { x0 = 0.f; x1 = 0.f; x2 = 0.f; }
            As[tap * 3 + 0][pxl] = x0;
            As[tap * 3 + 1][pxl] = x1;
            As[tap * 3 + 2][pxl] = x2;
        }
    }
    __syncthreads();

    int tx = tid & 7, ty = tid >> 3;
    float acc[4][4];
#pragma unroll
    for (int i = 0; i < 4; i++)
#pragma unroll
        for (int j = 0; j < 4; j++) acc[i][j] = 0.f;

#pragma unroll 9
    for (int k = 0; k < 27; k++) {
        float4 a = *(const float4*)&As[k][ty << 2];
        float4 b = *(const float4*)&Bs[k][tx << 2];
        acc[0][0] = fmaf(a.x, b.x, acc[0][0]); acc[0][1] = fmaf(a.x, b.y, acc[0][1]);
        acc[0][2] = fmaf(a.x, b.z, acc[0][2]); acc[0][3] = fmaf(a.x, b.w, acc[0][3]);
        acc[1][0] = fmaf(a.y, b.x, acc[1][0]); acc[1][1] = fmaf(a.y, b.y, acc[1][1]);
        acc[1][2] = fmaf(a.y, b.z, acc[1][2]); acc[1][3] = fmaf(a.y, b.w, acc[1][3]);
        acc[2][0] = fmaf(a.z, b.x, acc[2][0]); acc[2][1] = fmaf(a.z, b.y, acc[2][1]);
        acc[2][2] = fmaf(a.z, b.z, acc[2][2]); acc[2][3] = fmaf(a.z, b.w, acc[2][3]);
        acc[3][0] = fmaf(a.w, b.x, acc[3][0]); acc[3][1] = fmaf(a.w, b.y, acc[3][1]);
        acc[3][2] = fmaf(a.w, b.z, acc[3][2]); acc[3][3] = fmaf(a.w, b.w, acc[3][3]);
    }

    float4 bc = *(const float4*)(b1 + (tx << 2));
#pragma unroll
    for (int i = 0; i < 4; i++) {
        float4 o;
        o.x = eluf(acc[i][0] + bc.x);
        o.y = eluf(acc[i][1] + bc.y);
        o.z = eluf(acc[i][2] + bc.z);
        o.w = eluf(acc[i][3] + bc.w);
        *(float4*)(out + (size_t)(p0 + (ty << 2) + i) * 32 + (tx << 2)) = o;
    }
}

// conv2/conv3: in [n][IS][IS][32] -> out [n+off][OS][OS][32], stride2 pad1, ELU
template<int IS, int OS>
__global__ __launch_bounds__(256) void convg_k(const float* __restrict__ in,
    const float* __restrict__ wtb, const float* __restrict__ bias,
    float* __restrict__ out, int pOff)
{
    __shared__ float Bs[288 * 32];
    __shared__ float As[32][132];
    int tid = threadIdx.x;
    {
        const float4* src = (const float4*)wtb;
        float4* dst = (float4*)Bs;
#pragma unroll
        for (int r = 0; r < 9; r++) dst[tid + r * 256] = src[tid + r * 256];
    }
    const int OS2 = OS * OS;
    int p0 = blockIdx.x << 7;
    int c4 = tid & 7;
    int pn[4], pox[4], poy[4];
#pragma unroll
    for (int i = 0; i < 4; i++) {
        int px = (tid >> 3) + (i << 5);
        int p = p0 + px;
        int n = p / OS2;
        int rem = p - n * OS2;
        int ox = rem / OS;
        pn[i] = n; pox[i] = ox; poy[i] = rem - ox * OS;
    }

    int tx = tid & 7, ty = tid >> 3;
    float acc[4][4];
#pragma unroll
    for (int i = 0; i < 4; i++)
#pragma unroll
        for (int j = 0; j < 4; j++) acc[i][j] = 0.f;

    for (int k1 = 0; k1 < 3; k1++) {
        for (int k2 = 0; k2 < 3; k2++) {
            __syncthreads();
#pragma unroll
            for (int i = 0; i < 4; i++) {
                int px = (tid >> 3) + (i << 5);
                int u = 2 * pox[i] - 1 + k1;
                int v = 2 * poy[i] - 1 + k2;
                bool ok = (u >= 0) && (u < IS) && (v >= 0) && (v < IS);
                int uc = ok ? u : 0, vc = ok ? v : 0;
                float4 val = *(const float4*)(in +
                    ((size_t)((pn[i] * IS + uc) * IS + vc)) * 32 + (c4 << 2));
                if (!ok) { val.x = 0.f; val.y = 0.f; val.z = 0.f; val.w = 0.f; }
                As[(c4 << 2) + 0][px] = val.x;
                As[(c4 << 2) + 1][px] = val.y;
                As[(c4 << 2) + 2][px] = val.z;
                As[(c4 << 2) + 3][px] = val.w;
            }
            __syncthreads();
            const float* bsrc = Bs + (size_t)((k1 * 3 + k2) << 5) * 32;
#pragma unroll 8
            for (int k = 0; k < 32; k++) {
                float4 a = *(const float4*)&As[k][ty << 2];
                float4 b = *(const float4*)&bsrc[(k << 5) + (tx << 2)];
                acc[0][0] = fmaf(a.x, b.x, acc[0][0]); acc[0][1] = fmaf(a.x, b.y, acc[0][1]);
                acc[0][2] = fmaf(a.x, b.z, acc[0][2]); acc[0][3] = fmaf(a.x, b.w, acc[0][3]);
                acc[1][0] = fmaf(a.y, b.x, acc[1][0]); acc[1][1] = fmaf(a.y, b.y, acc[1][1]);
                acc[1][2] = fmaf(a.y, b.z, acc[1][2]); acc[1][3] = fmaf(a.y, b.w, acc[1][3]);
                acc[2][0] = fmaf(a.z, b.x, acc[2][0]); acc[2][1] = fmaf(a.z, b.y, acc[2][1]);
                acc[2][2] = fmaf(a.z, b.z, acc[2][2]); acc[2][3] = fmaf(a.z, b.w, acc[2][3]);
                acc[3][0] = fmaf(a.w, b.x, acc[3][0]); acc[3][1] = fmaf(a.w, b.y, acc[3][1]);
                acc[3][2] = fmaf(a.w, b.z, acc[3][2]); acc[3][3] = fmaf(a.w, b.w, acc[3][3]);
            }
        }
    }

    float4 bc = *(const float4*)(bias + (tx << 2));
#pragma unroll
    for (int i = 0; i < 4; i++) {
        float4 o;
        o.x = eluf(acc[i][0] + bc.x);
        o.y = eluf(acc[i][1] + bc.y);
        o.z = eluf(acc[i][2] + bc.z);
        o.w = eluf(acc[i][3] + bc.w);
        *(float4*)(out + (size_t)(pOff + p0 + (ty << 2) + i) * 32 + (tx << 2)) = o;
    }
}

// fw1t[h][p*32+co] = fw1[h][co*121+p] (match conv3 K-order), direct to bf16 hi/lo
__global__ __launch_bounds__(256) void repack_fw1(const float* __restrict__ fw1,
    unsigned short* __restrict__ hi, unsigned short* __restrict__ lo)
{
    __shared__ float row[3872];
    int h = blockIdx.x;
    const float* src = fw1 + (size_t)h * 3872;
    for (int j = threadIdx.x; j < 3872; j += 256) row[j] = src[j];
    __syncthreads();
    unsigned short* dh = hi + (size_t)h * 3872;
    unsigned short* dl = lo + (size_t)h * 3872;
    for (int j = threadIdx.x; j < 3872; j += 256) {
        int p = j >> 5, co = j & 31;
        unsigned short hb, lb;
        bfsplit(row[co * 121 + p], hb, lb);
        dh[j] = hb;
        dl[j] = lb;
    }
}

// C[m][n] = sum_k A[m][k]*B[n][k] via split-bf16 MFMA.
// A,B given as hi/lo bf16 planes; product = ahi*bhi + ahi*blo + alo*bhi.
// Block 256 thr = 4 waves (2M x 2N); block tile 64(M) x 128(N); wave 32x64:
// R=2 row-subtiles x C=4 col-subtiles of 16x16, K-step 32 (mfma_f32_16x16x32_bf16).
// Frag layout (16x16x32): lane l holds row/col (l&15), k = (l>>4)*8 + 0..7
// (8 consecutive bf16 = one dwordx4). C/D: col=lane&15, row=(lane>>4)*4+reg.
// No LDS: frags direct from L1/L2 (each frag load = 16 fully-used 64B lines).
__global__ __launch_bounds__(256) void gemm_mfma(
    const unsigned short* __restrict__ Ahi, const unsigned short* __restrict__ Alo,
    const unsigned short* __restrict__ Bhi, const unsigned short* __restrict__ Blo,
    float* __restrict__ Cbase, size_t Cstride, int N, int K, int Nt, int kchunk)
{
    int tid = threadIdx.x;
    int w = tid >> 6, l = tid & 63;
    int bid = blockIdx.x;
    int nt = bid % Nt, mt = bid / Nt;
    int m0 = mt << 6, n0 = nt << 7;
    int kbeg = blockIdx.z * kchunk;
    int kend = kbeg + kchunk;
    if (kend > K) kend = K;
    int steps = (kend - kbeg) >> 5;
    float* C = Cbase + (size_t)blockIdx.z * Cstride;

    int wm = (w & 1) << 5;          // wave row offset within block: 0/32
    int wn = (w >> 1) << 6;         // wave col offset within block: 0/64
    int lr = l & 15;
    int lk = (l >> 4) << 3;

    size_t aoff = (size_t)(m0 + wm + lr) * K + kbeg + lk;
    size_t boff = (size_t)(n0 + wn + lr) * K + kbeg + lk;
    const unsigned short* pah = Ahi + aoff;
    const unsigned short* pal = Alo + aoff;
    const unsigned short* pbh = Bhi + boff;
    const unsigned short* pbl = Blo + boff;
    const size_t rstr = (size_t)16 * K;   // subtile stride (16 rows/cols)

    f32x4 acc[2][4];
#pragma unroll
    for (int i = 0; i < 2; i++)
#pragma unroll
        for (int j = 0; j < 4; j++) acc[i][j] = (f32x4){0.f, 0.f, 0.f, 0.f};

    for (int s = 0; s < steps; s++) {
        int ko = s << 5;
        bf16x8 ah0 = *(const bf16x8*)(pah + ko);
        bf16x8 ah1 = *(const bf16x8*)(pah + rstr + ko);
        bf16x8 al0 = *(const bf16x8*)(pal + ko);
        bf16x8 al1 = *(const bf16x8*)(pal + rstr + ko);
        bf16x8 bh[4], bl[4];
#pragma unroll
        for (int c = 0; c < 4; c++) {
            bh[c] = *(const bf16x8*)(pbh + (size_t)c * rstr + ko);
            bl[c] = *(const bf16x8*)(pbl + (size_t)c * rstr + ko);
        }
        // pass 1: alo*bhi  (acc reuse distance 8 mfmas between passes)
#pragma unroll
        for (int c = 0; c < 4; c++) {
            acc[0][c] = __builtin_amdgcn_mfma_f32_16x16x32_bf16(al0, bh[c], acc[0][c], 0, 0, 0);
            acc[1][c] = __builtin_amdgcn_mfma_f32_16x16x32_bf16(al1, bh[c], acc[1][c], 0, 0, 0);
        }
        // pass 2: ahi*blo
#pragma unroll
        for (int c = 0; c < 4; c++) {
            acc[0][c] = __builtin_amdgcn_mfma_f32_16x16x32_bf16(ah0, bl[c], acc[0][c], 0, 0, 0);
            acc[1][c] = __builtin_amdgcn_mfma_f32_16x16x32_bf16(ah1, bl[c], acc[1][c], 0, 0, 0);
        }
        // pass 3: ahi*bhi
#pragma unroll
        for (int c = 0; c < 4; c++) {
            acc[0][c] = __builtin_amdgcn_mfma_f32_16x16x32_bf16(ah0, bh[c], acc[0][c], 0, 0, 0);
            acc[1][c] = __builtin_amdgcn_mfma_f32_16x16x32_bf16(ah1, bh[c], acc[1][c], 0, 0, 0);
        }
    }

    int rrow = (l >> 4) << 2;
#pragma unroll
    for (int ri = 0; ri < 2; ri++) {
#pragma unroll
        for (int ci = 0; ci < 4; ci++) {
            int row = m0 + wm + (ri << 4) + rrow;
            int col = n0 + wn + (ci << 4) + lr;
            float* cp = C + (size_t)row * N + col;
#pragma unroll
            for (int r = 0; r < 4; r++) cp[(size_t)r * N] = acc[ri][ci][r];
        }
    }
}

// out[i] = relu(bias[i%1024] + sum_z p[i + z*stride]) over 1048576 elements
__global__ __launch_bounds__(256) void bias_relu_sum(const float* __restrict__ p,
    size_t stride, int nz, const float* __restrict__ b, float* __restrict__ out)
{
    int i = blockIdx.x * 256 + threadIdx.x;
    float v = b[i & 1023];
    for (int z = 0; z < nz; z++) v += p[i + (size_t)z * stride];
    out[i] = v > 0.f ? v : 0.f;
}

// one LSTM step for one layer. 512 blocks = 512 unit-pairs; register-tiled
// (4 batches x 1 unit x 4 gates per thread); h tile XOR bank-swizzled.
// gx pre-activation now a SINGLE array [1024][4096] (mfma gemm, no splitk).
__global__ __launch_bounds__(256) void lstm_step(
    const float* __restrict__ gx,      // [1024][4096] rows t*32+b
    const float* __restrict__ whh,     // [4096][1024]
    const float* __restrict__ bsum,    // [4096] (caller offsets for layer)
    const float* __restrict__ hprev,   // rows b*1024 (pre-offset for t/layer)
    const float* __restrict__ cprev,   // idx b*1024+j (pre-offset for layer)
    float* __restrict__ cout,          // idx b*1024+j
    float* __restrict__ Hout,          // rows t*32+b
    const unsigned char* __restrict__ dmask, // &done[t*32]
    int t)
{
    __shared__ float Hs[32][132];      // h chunk: 32 batches x 128 cols (swizzled)
    __shared__ float Ws[8][132];       // w chunk: 2 units x 4 gates x 128 cols
    __shared__ float4 part[16][65];    // k-slice partials, odd stride
    int tid = threadIdx.x;
    int bg = tid & 7;
    int u  = (tid >> 3) & 1;
    int s  = tid >> 4;
    int jb = (int)blockIdx.x << 1;
    int r0 = tid >> 5;
    int c40 = tid & 31;

    float nds[4];
#pragma unroll
    for (int rep = 0; rep < 4; rep++) nds[rep] = dmask[r0 + (rep << 3)] ? 0.f : 1.f;

    int wuu = tid >> 7, wg = (tid >> 5) & 3, wc = tid & 31;
    const float* wsrc = whh + ((size_t)(wg << 10) + jb + wuu) * 1024 + (wc << 2);

    float acc[4][4];
#pragma unroll
    for (int i = 0; i < 4; i++)
#pragma unroll
        for (int g = 0; g < 4; g++) acc[i][g] = 0.f;

    for (int kt = 0; kt < 8; kt++) {
        if (kt) __syncthreads();
#pragma unroll
        for (int rep = 0; rep < 4; rep++) {
            int r = r0 + (rep << 3);
            float4 h4 = *(const float4*)(hprev + (size_t)r * 1024 + (kt << 7) + (c40 << 2));
            float nd = nds[rep];
            h4.x *= nd; h4.y *= nd; h4.z *= nd; h4.w *= nd;
            *(float4*)&Hs[r][(c40 ^ ((r >> 2) & 7)) << 2] = h4;
        }
        *(float4*)&Ws[(wuu << 2) + wg][wc << 2] = *(const float4*)(wsrc + (kt << 7));
        __syncthreads();
#pragma unroll
        for (int kq = 0; kq < 2; kq++) {
            int col4 = (s << 1) + kq;
            float4 w0 = *(const float4*)&Ws[(u << 2) + 0][col4 << 2];
            float4 w1 = *(const float4*)&Ws[(u << 2) + 1][col4 << 2];
            float4 w2 = *(const float4*)&Ws[(u << 2) + 2][col4 << 2];
            float4 w3 = *(const float4*)&Ws[(u << 2) + 3][col4 << 2];
#pragma unroll
            for (int i = 0; i < 4; i++) {
                float4 h4 = *(const float4*)&Hs[(bg << 2) + i][(col4 ^ bg) << 2];
                acc[i][0] = fmaf(h4.x, w0.x, fmaf(h4.y, w0.y, fmaf(h4.z, w0.z, fmaf(h4.w, w0.w, acc[i][0]))));
                acc[i][1] = fmaf(h4.x, w1.x, fmaf(h4.y, w1.y, fmaf(h4.z, w1.z, fmaf(h4.w, w1.w, acc[i][1]))));
                acc[i][2] = fmaf(h4.x, w2.x, fmaf(h4.y, w2.y, fmaf(h4.z, w2.z, fmaf(h4.w, w2.w, acc[i][2]))));
                acc[i][3] = fmaf(h4.x, w3.x, fmaf(h4.y, w3.y, fmaf(h4.z, w3.z, fmaf(h4.w, w3.w, acc[i][3]))));
            }
        }
    }

#pragma unroll
    for (int i = 0; i < 4; i++) {
        float4 pv; pv.x = acc[i][0]; pv.y = acc[i][1]; pv.z = acc[i][2]; pv.w = acc[i][3];
        part[s][(((bg << 2) + i) << 1) + u] = pv;
    }
    __syncthreads();
    if (tid < 64) {
        int b = tid & 31, uu = tid >> 5;
        float4 sum; sum.x = 0.f; sum.y = 0.f; sum.z = 0.f; sum.w = 0.f;
#pragma unroll
        for (int sl = 0; sl < 16; sl++) {
            float4 pv = part[sl][(b << 1) + uu];
            sum.x += pv.x; sum.y += pv.y; sum.z += pv.z; sum.w += pv.w;
        }
        int j = jb + uu;
        int row = (t << 5) + b;
        const float* gp = gx + (size_t)row * 4096 + j;
        float g0 = sum.x + gp[0]    + bsum[j];
        float g1 = sum.y + gp[1024] + bsum[j + 1024];
        float g2 = sum.z + gp[2048] + bsum[j + 2048];
        float g3 = sum.w + gp[3072] + bsum[j + 3072];
        float nd = dmask[b] ? 0.f : 1.f;
        float cp = cprev[(size_t)b * 1024 + j] * nd;
        float si = 1.f / (1.f + expf(-g0));
        float sf = 1.f / (1.f + expf(-g1));
        float so = 1.f / (1.f + expf(-g3));
        float cn = sf * cp + si * tanhf(g2);
        float hn = so * tanhf(cn);
        cout[(size_t)b * 1024 + j] = cn;
        Hout[(size_t)row * 1024 + j] = hn;
    }
}

__global__ __launch_bounds__(256) void heads_k(const float* __restrict__ Hc,
    const float* __restrict__ pw, const float* __restrict__ pb,
    const float* __restrict__ bw, const float* __restrict__ bbias,
    float* __restrict__ out)
{
    __shared__ float red[8][264];
    int n = blockIdx.x, tid = threadIdx.x;
    float4 x4 = *(const float4*)(Hc + (size_t)n * 1024 + (tid << 2));
#pragma unroll
    for (int a = 0; a < 7; a++) {
        float4 w4 = *(const float4*)(pw + (size_t)a * 1024 + (tid << 2));
        red[a][tid] = x4.x * w4.x + x4.y * w4.y + x4.z * w4.z + x4.w * w4.w;
    }
    {
        float4 w4 = *(const float4*)(bw + (tid << 2));
        red[7][tid] = x4.x * w4.x + x4.y * w4.y + x4.z * w4.z + x4.w * w4.w;
    }
    __syncthreads();
    for (int off = 128; off > 0; off >>= 1) {
        if (tid < off) {
#pragma unroll
            for (int a = 0; a < 8; a++) red[a][tid] += red[a][tid + off];
        }
        __syncthreads();
    }
    if (tid == 0) {
        float best = -1e30f; int bi = 0;
        for (int a = 0; a < 7; a++) {
            float L = red[a][0] + pb[a];
            out[n * 7 + a] = L;
            if (L > best) { best = L; bi = a; }
        }
        out[7168 + n] = red[7][0] + bbias[0];
        out[8192 + n] = (float)bi;
    }
}

__global__ __launch_bounds__(256) void final_copy(const float* __restrict__ H0,
    const float* __restrict__ H1, const float* __restrict__ cst, float* __restrict__ out)
{
    int i = blockIdx.x * 256 + threadIdx.x;   // 131072 exact
    if (i < 65536) {
        int l = i >> 15;
        int rem = i & 32767;
        const float* H = l ? H1 : H0;
        out[9216 + i] = H[(size_t)(31 * 32) * 1024 + rem];
    } else {
        out[74752 + (i - 65536)] = cst[i - 65536];
    }
}

extern "C" void kernel_launch(void* const* d_in, const int* in_sizes, int n_in,
                              void* d_out, int out_size, void* d_ws, size_t ws_size,
                              hipStream_t stream)
{
    (void)in_sizes; (void)n_in; (void)out_size; (void)ws_size;
    const float* frame = (const float*)d_in[0];
    const unsigned char* done8 = (const unsigned char*)d_in[1];
    const float* h0   = (const float*)d_in[2];
    const float* c0   = (const float*)d_in[3];
    const float* cw1  = (const float*)d_in[4];
    const float* cb1  = (const float*)d_in[5];
    const float* cw2  = (const float*)d_in[6];
    const float* cb2  = (const float*)d_in[7];
    const float* cw3  = (const float*)d_in[8];
    const float* cb3  = (const float*)d_in[9];
    const float* fw1  = (const float*)d_in[10];
    const float* fb1  = (const float*)d_in[11];
    const float* fw2  = (const float*)d_in[12];
    const float* fb2  = (const float*)d_in[13];
    const float* wih0 = (const float*)d_in[14];
    const float* whh0 = (const float*)d_in[15];
    const float* bih0 = (const float*)d_in[16];
    const float* bhh0 = (const float*)d_in[17];
    const float* wih1 = (const float*)d_in[18];
    const float* whh1 = (const float*)d_in[19];
    const float* bih1 = (const float*)d_in[20];
    const float* bhh1 = (const float*)d_in[21];
    const float* pw   = (const float*)d_in[22];
    const float* pb   = (const float*)d_in[23];
    const float* bw   = (const float*)d_in[24];
    const float* bbias= (const float*)d_in[25];

    float* ws   = (float*)d_ws;
    float* A    = ws;                      // 14,450,688
    float* Bv   = A + 14450688;            //  7,225,344
    float* fc1  = Bv + 7225344;            //  1,048,576
    float* cin  = fc1 + 1048576;           //  1,048,576
    float* H0   = cin + 1048576;           //  1,048,576
    float* H1   = H0 + 1048576;            //  1,048,576
    float* cst  = H1 + 1048576;            //     65,536
    float* bsum = cst + 65536;             //      8,192
    float* wt   = bsum + 8192;             //     19,296
    float* conv2f = A;
    float* conv3o = Bv;                    // [1024][3872] fp32
    // FC1 operands (bf16 planes; conv2f dead after conv3)
    unsigned short* c3hi = (unsigned short*)(A);
    unsigned short* c3lo = (unsigned short*)(A + 1982464);
    unsigned short* f1hi = (unsigned short*)(A + 3964928);
    unsigned short* f1lo = (unsigned short*)(A + 5947392);
    float* fc1p = Bv;                      // FC1 partials 6x1,048,576 (conv3o dead)
    // FC2 operands (FC1 partials dead after relu)
    unsigned short* fc1hi = (unsigned short*)(Bv);
    unsigned short* fc1lo = (unsigned short*)(Bv + 524288);
    unsigned short* fw2hi = (unsigned short*)(Bv + 1048576);
    unsigned short* fw2lo = (unsigned short*)(Bv + 1572864);
    float* fc2p = A;                       // FC2 partials 4x1,048,576 (c3/f1 dead)
    // gx phase (FC2 partials dead after relu)
    unsigned short* cinhi = (unsigned short*)(Bv + 2097152);
    unsigned short* cinlo = (unsigned short*)(Bv + 2621440);
    unsigned short* h0hi  = (unsigned short*)(Bv + 3145728);
    unsigned short* h0lo  = (unsigned short*)(Bv + 3670016);
    unsigned short* w0hi = (unsigned short*)(A);
    unsigned short* w0lo = (unsigned short*)(A + 2097152);
    unsigned short* w1hi = (unsigned short*)(A + 4194304);
    unsigned short* w1lo = (unsigned short*)(A + 6291456);
    float* gx = A + 8388608;               // [1024][4096] fp32, ends 12,582,912
    float* out = (float*)d_out;

    repack_w<<<76, 256, 0, stream>>>(cw1, cw2, cw3, wt);
    bsum_k<<<32, 256, 0, stream>>>(bih0, bhh0, bih1, bhh1, bsum);

    for (int ch = 0; ch < 8; ch++) {
        conv1_k<<<1764, 256, 0, stream>>>(frame, wt, cb1, Bv, ch * 128);
        convg_k<42, 21><<<441, 256, 0, stream>>>(Bv, wt + 864, cb2, conv2f, ch * 128 * 441);
    }
    convg_k<21, 11><<<968, 256, 0, stream>>>(conv2f, wt + 10080, cb3, conv3o, 0);

    // convert conv3o -> bf16 planes; repack fw1 -> bf16 planes
    cvt_split<<<1936, 256, 0, stream>>>(conv3o, c3hi, c3lo, 3964928);
    repack_fw1<<<1024, 256, 0, stream>>>(fw1, f1hi, f1lo);

    // FC1: M=1024 N=1024 K=3872, tile 64x128 -> Mt=16,Nt=8 (128 blocks), splitk6
    { dim3 g(128, 1, 6); gemm_mfma<<<g, 256, 0, stream>>>(c3hi, c3lo, f1hi, f1lo,
        fc1p, 1048576, 1024, 3872, 8, 672); }
    bias_relu_sum<<<4096, 256, 0, stream>>>(fc1p, 1048576, 6, fb1, fc1);

    // FC2: K=1024, splitk4
    cvt_split<<<512, 256, 0, stream>>>(fc1, fc1hi, fc1lo, 1048576);
    cvt_split<<<512, 256, 0, stream>>>(fw2, fw2hi, fw2lo, 1048576);
    { dim3 g(128, 1, 4); gemm_mfma<<<g, 256, 0, stream>>>(fc1hi, fc1lo, fw2hi, fw2lo,
        fc2p, 1048576, 1024, 1024, 8, 256); }
    bias_relu_sum<<<4096, 256, 0, stream>>>(fc2p, 1048576, 4, fb2, cin);

    // gx0: M=1024 N=4096 K=1024, Mt=16,Nt=32 -> 512 blocks, no splitk
    cvt_split<<<512, 256, 0, stream>>>(cin, cinhi, cinlo, 1048576);
    cvt_split<<<2048, 256, 0, stream>>>(wih0, w0hi, w0lo, 4194304);
    cvt_split<<<2048, 256, 0, stream>>>(wih1, w1hi, w1lo, 4194304);
    { dim3 g(512, 1, 1); gemm_mfma<<<g, 256, 0, stream>>>(cinhi, cinlo, w0hi, w0lo,
        gx, 0, 4096, 1024, 32, 1024); }
    for (int t = 0; t < 32; t++) {
        const float* hp = t ? (H0 + (size_t)(t - 1) * 32768) : h0;
        const float* cp = t ? cst : c0;
        lstm_step<<<512, 256, 0, stream>>>(gx, whh0, bsum, hp, cp, cst, H0, done8 + t * 32, t);
    }
    // gx1: A = H0 (bf16), B = wih1 (bf16), overwrite gx
    cvt_split<<<512, 256, 0, stream>>>(H0, h0hi, h0lo, 1048576);
    { dim3 g(512, 1, 1); gemm_mfma<<<g, 256, 0, stream>>>(h0hi, h0lo, w1hi, w1lo,
        gx, 0, 4096, 1024, 32, 1024); }
    for (int t = 0; t < 32; t++) {
        const float* hp = t ? (H1 + (size_t)(t - 1) * 32768) : (h0 + 32768);
        const float* cp = t ? (cst + 32768) : (c0 + 32768);
        lstm_step<<<512, 256, 0, stream>>>(gx, whh1, bsum + 4096, hp, cp, cst + 32768, H1, done8 + t * 32, t);
    }
    heads_k<<<1024, 256, 0, stream>>>(H1, pw, pb, bw, bbias, out);
    final_copy<<<512, 256, 0, stream>>>(H0, H1, cst, out);
}

// Round 8
// 1696.071 us; speedup vs baseline: 4.0863x; 1.0045x over previous
//
#include <hip/hip_runtime.h>
#include <cmath>

// ---------------- problem constants ----------------
// T=32 B=32 H=W=84 C=3 HID=1024, conv: 84->42->21->11, CONV_OUT=3872
// outputs: logits[1024*7] | baseline[1024] | action[1024] | h_fin[65536] | c_fin[65536]
// GEMMs: split-bf16 MFMA (hi+lo planes, 3 mfma passes ~ fp32 precision).

// ---------------- ws layout (floats) ----------------
// A (14,450,688): conv2f full; then {c3hi,c3lo,f1hi,f1lo} bf16 for FC1;
//   then FC2 partials (4x1,048,576); then {w0hi,w0lo,w1hi,w1lo}@0..8,388,608
//   + gx fp32 [1024][4096] @8,388,608..12,582,912
// Bv (7,225,344): conv1 chunk; conv3o fp32; FC1 partials (6x1,048,576);
//   then {fc1hi,fc1lo,fw2hi,fw2lo,cinhi,cinlo,h0hi,h0lo} bf16
// fc1/cin/H0/H1: 1,048,576 each; cst 65,536; bsum 8,192; wt 19,296

typedef short bf16x8 __attribute__((ext_vector_type(8)));
typedef float f32x4 __attribute__((ext_vector_type(4)));

__device__ __forceinline__ float eluf(float v) {
    return v > 0.f ? v : expm1f(v);
}

// round-to-nearest-even fp32 -> bf16 bits
__device__ __forceinline__ unsigned short f2bf(float x) {
    unsigned int u = __float_as_uint(x);
    u += 0x7FFFu + ((u >> 16) & 1u);
    return (unsigned short)(u >> 16);
}

// split x into hi + lo bf16 planes (x ~= hi + lo, error ~2^-17 rel)
__device__ __forceinline__ void bfsplit(float x, unsigned short& h, unsigned short& l) {
    unsigned short hb = f2bf(x);
    float hf = __uint_as_float((unsigned int)hb << 16);
    h = hb;
    l = f2bf(x - hf);
}

// weights repacked k-major: wt[(tap*CI+ci)*32 + co]
__global__ __launch_bounds__(256) void repack_w(const float* __restrict__ w1,
    const float* __restrict__ w2, const float* __restrict__ w3, float* __restrict__ wt)
{
    int i = blockIdx.x * 256 + threadIdx.x;
    if (i < 864) {
        int co = i & 31, r = i >> 5;
        int tap = r / 3, ci = r - tap * 3;
        int k1 = tap / 3, k2 = tap - k1 * 3;
        wt[i] = w1[co * 27 + ci * 9 + k1 * 3 + k2];
    } else if (i < 10080) {
        int o = i - 864;
        int co = o & 31, r = o >> 5;
        int tap = r >> 5, ci = r & 31;
        int k1 = tap / 3, k2 = tap - k1 * 3;
        wt[i] = w2[co * 288 + ci * 9 + k1 * 3 + k2];
    } else if (i < 19296) {
        int o = i - 10080;
        int co = o & 31, r = o >> 5;
        int tap = r >> 5, ci = r & 31;
        int k1 = tap / 3, k2 = tap - k1 * 3;
        wt[i] = w3[co * 288 + ci * 9 + k1 * 3 + k2];
    }
}

__global__ __launch_bounds__(256) void bsum_k(const float* __restrict__ bih0,
    const float* __restrict__ bhh0, const float* __restrict__ bih1,
    const float* __restrict__ bhh1, float* __restrict__ bsum)
{
    int i = blockIdx.x * 256 + threadIdx.x;
    if (i < 4096) bsum[i] = bih0[i] + bhh0[i];
    else if (i < 8192) bsum[i] = bih1[i - 4096] + bhh1[i - 4096];
}

// elementwise fp32 -> bf16 hi/lo planes, 8 elems/thread, exact grids
__global__ __launch_bounds__(256) void cvt_split(const float* __restrict__ src,
    unsigned short* __restrict__ hi, unsigned short* __restrict__ lo, int n)
{
    int i = (blockIdx.x * 256 + threadIdx.x) << 3;
    if (i >= n) return;
    float4 v0 = *(const float4*)(src + i);
    float4 v1 = *(const float4*)(src + i + 4);
    float vs[8] = {v0.x, v0.y, v0.z, v0.w, v1.x, v1.y, v1.z, v1.w};
    bf16x8 hv, lv;
#pragma unroll
    for (int j = 0; j < 8; j++) {
        unsigned short hb, lb;
        bfsplit(vs[j], hb, lb);
        hv[j] = (short)hb;
        lv[j] = (short)lb;
    }
    *(bf16x8*)(hi + i) = hv;
    *(bf16x8*)(lo + i) = lv;
}

// conv1: frame [n][h][w][3] -> out [nl][ox][oy][32], 42x42, stride2 pad1, ELU
__global__ __launch_bounds__(256) void conv1_k(const float* __restrict__ frame,
    const float* __restrict__ w1t, const float* __restrict__ b1,
    float* __restrict__ out, int n0)
{
    __shared__ float As[27][132];
    __shared__ float Bs[27][32];
    int tid = threadIdx.x;
    if (tid < 216) ((float4*)Bs)[tid] = ((const float4*)w1t)[tid];

    int p0 = blockIdx.x << 7;
    int pxl = tid & 127;
    int half = tid >> 7;
    {
        int p = p0 + pxl;
        int nl = p / 1764;
        int rem = p - nl * 1764;
        int ox = rem / 42;
        int oy = rem - ox * 42;
        const float* fr = frame + (size_t)(n0 + nl) * 21168;
        for (int tap = half; tap < 9; tap += 2) {
            int k1 = tap / 3, k2 = tap - k1 * 3;
            int u = 2 * ox - 1 + k1;
            int v = 2 * oy - 1 + k2;
            bool ok = (u >= 0) && (u < 84) && (v >= 0) && (v < 84);
            int uc = ok ? u : 0, vc = ok ? v : 0;
            const float* fp = fr + (vc * 84 + uc) * 3;
            float x0 = fp[0], x1 = fp[1], x2 = fp[2];
            if (!ok) { x0 = 0.f; x1 = 0.f; x2 = 0.f; }
            As[tap * 3 + 0][pxl] = x0;
            As[tap * 3 + 1][pxl] = x1;
            As[tap * 3 + 2][pxl] = x2;
        }
    }
    __syncthreads();

    int tx = tid & 7, ty = tid >> 3;
    float acc[4][4];
#pragma unroll
    for (int i = 0; i < 4; i++)
#pragma unroll
        for (int j = 0; j < 4; j++) acc[i][j] = 0.f;

#pragma unroll 9
    for (int k = 0; k < 27; k++) {
        float4 a = *(const float4*)&As[k][ty << 2];
        float4 b = *(const float4*)&Bs[k][tx << 2];
        acc[0][0] = fmaf(a.x, b.x, acc[0][0]); acc[0][1] = fmaf(a.x, b.y, acc[0][1]);
        acc[0][2] = fmaf(a.x, b.z, acc[0][2]); acc[0][3] = fmaf(a.x, b.w, acc[0][3]);
        acc[1][0] = fmaf(a.y, b.x, acc[1][0]); acc[1][1] = fmaf(a.y, b.y, acc[1][1]);
        acc[1][2] = fmaf(a.y, b.z, acc[1][2]); acc[1][3] = fmaf(a.y, b.w, acc[1][3]);
        acc[2][0] = fmaf(a.z, b.x, acc[2][0]); acc[2][1] = fmaf(a.z, b.y, acc[2][1]);
        acc[2][2] = fmaf(a.z, b.z, acc[2][2]); acc[2][3] = fmaf(a.z, b.w, acc[2][3]);
        acc[3][0] = fmaf(a.w, b.x, acc[3][0]); acc[3][1] = fmaf(a.w, b.y, acc[3][1]);
        acc[3][2] = fmaf(a.w, b.z, acc[3][2]); acc[3][3] = fmaf(a.w, b.w, acc[3][3]);
    }

    float4 bc = *(const float4*)(b1 + (tx << 2));
#pragma unroll
    for (int i = 0; i < 4; i++) {
        float4 o;
        o.x = eluf(acc[i][0] + bc.x);
        o.y = eluf(acc[i][1] + bc.y);
        o.z = eluf(acc[i][2] + bc.z);
        o.w = eluf(acc[i][3] + bc.w);
        *(float4*)(out + (size_t)(p0 + (ty << 2) + i) * 32 + (tx << 2)) = o;
    }
}

// conv2/conv3: in [n][IS][IS][32] -> out [n+off][OS][OS][32], stride2 pad1, ELU
template<int IS, int OS>
__global__ __launch_bounds__(256) void convg_k(const float* __restrict__ in,
    const float* __restrict__ wtb, const float* __restrict__ bias,
    float* __restrict__ out, int pOff)
{
    __shared__ float Bs[288 * 32];
    __shared__ float As[32][132];
    int tid = threadIdx.x;
    {
        const float4* src = (const float4*)wtb;
        float4* dst = (float4*)Bs;
#pragma unroll
        for (int r = 0; r < 9; r++) dst[tid + r * 256] = src[tid + r * 256];
    }
    const int OS2 = OS * OS;
    int p0 = blockIdx.x << 7;
    int c4 = tid & 7;
    int pn[4], pox[4], poy[4];
#pragma unroll
    for (int i = 0; i < 4; i++) {
        int px = (tid >> 3) + (i << 5);
        int p = p0 + px;
        int n = p / OS2;
        int rem = p - n * OS2;
        int ox = rem / OS;
        pn[i] = n; pox[i] = ox; poy[i] = rem - ox * OS;
    }

    int tx = tid & 7, ty = tid >> 3;
    float acc[4][4];
#pragma unroll
    for (int i = 0; i < 4; i++)
#pragma unroll
        for (int j = 0; j < 4; j++) acc[i][j] = 0.f;

    for (int k1 = 0; k1 < 3; k1++) {
        for (int k2 = 0; k2 < 3; k2++) {
            __syncthreads();
#pragma unroll
            for (int i = 0; i < 4; i++) {
                int px = (tid >> 3) + (i << 5);
                int u = 2 * pox[i] - 1 + k1;
                int v = 2 * poy[i] - 1 + k2;
                bool ok = (u >= 0) && (u < IS) && (v >= 0) && (v < IS);
                int uc = ok ? u : 0, vc = ok ? v : 0;
                float4 val = *(const float4*)(in +
                    ((size_t)((pn[i] * IS + uc) * IS + vc)) * 32 + (c4 << 2));
                if (!ok) { val.x = 0.f; val.y = 0.f; val.z = 0.f; val.w = 0.f; }
                As[(c4 << 2) + 0][px] = val.x;
                As[(c4 << 2) + 1][px] = val.y;
                As[(c4 << 2) + 2][px] = val.z;
                As[(c4 << 2) + 3][px] = val.w;
            }
            __syncthreads();
            const float* bsrc = Bs + (size_t)((k1 * 3 + k2) << 5) * 32;
#pragma unroll 8
            for (int k = 0; k < 32; k++) {
                float4 a = *(const float4*)&As[k][ty << 2];
                float4 b = *(const float4*)&bsrc[(k << 5) + (tx << 2)];
                acc[0][0] = fmaf(a.x, b.x, acc[0][0]); acc[0][1] = fmaf(a.x, b.y, acc[0][1]);
                acc[0][2] = fmaf(a.x, b.z, acc[0][2]); acc[0][3] = fmaf(a.x, b.w, acc[0][3]);
                acc[1][0] = fmaf(a.y, b.x, acc[1][0]); acc[1][1] = fmaf(a.y, b.y, acc[1][1]);
                acc[1][2] = fmaf(a.y, b.z, acc[1][2]); acc[1][3] = fmaf(a.y, b.w, acc[1][3]);
                acc[2][0] = fmaf(a.z, b.x, acc[2][0]); acc[2][1] = fmaf(a.z, b.y, acc[2][1]);
                acc[2][2] = fmaf(a.z, b.z, acc[2][2]); acc[2][3] = fmaf(a.z, b.w, acc[2][3]);
                acc[3][0] = fmaf(a.w, b.x, acc[3][0]); acc[3][1] = fmaf(a.w, b.y, acc[3][1]);
                acc[3][2] = fmaf(a.w, b.z, acc[3][2]); acc[3][3] = fmaf(a.w, b.w, acc[3][3]);
            }
        }
    }

    float4 bc = *(const float4*)(bias + (tx << 2));
#pragma unroll
    for (int i = 0; i < 4; i++) {
        float4 o;
        o.x = eluf(acc[i][0] + bc.x);
        o.y = eluf(acc[i][1] + bc.y);
        o.z = eluf(acc[i][2] + bc.z);
        o.w = eluf(acc[i][3] + bc.w);
        *(float4*)(out + (size_t)(pOff + p0 + (ty << 2) + i) * 32 + (tx << 2)) = o;
    }
}

// fw1t[h][p*32+co] = fw1[h][co*121+p] (match conv3 K-order), direct to bf16 hi/lo
__global__ __launch_bounds__(256) void repack_fw1(const float* __restrict__ fw1,
    unsigned short* __restrict__ hi, unsigned short* __restrict__ lo)
{
    __shared__ float row[3872];
    int h = blockIdx.x;
    const float* src = fw1 + (size_t)h * 3872;
    for (int j = threadIdx.x; j < 3872; j += 256) row[j] = src[j];
    __syncthreads();
    unsigned short* dh = hi + (size_t)h * 3872;
    unsigned short* dl = lo + (size_t)h * 3872;
    for (int j = threadIdx.x; j < 3872; j += 256) {
        int p = j >> 5, co = j & 31;
        unsigned short hb, lb;
        bfsplit(row[co * 121 + p], hb, lb);
        dh[j] = hb;
        dl[j] = lb;
    }
}

// C[m][n] = sum_k A[m][k]*B[n][k] via split-bf16 MFMA.
// Block 256 thr = 4 waves (2M x 2N); block tile 64(M) x 128(N); wave 32x64:
// R=2 x C=4 subtiles of 16x16, K-step 32 (mfma_f32_16x16x32_bf16).
// REGISTER DOUBLE-BUFFER: next k-step's 12 fragments are loaded BEFORE the
// current step's 24 MFMAs (r6 measured MfmaUtil=10% latency-stall: 12 dependent
// L2 loads ~350cyc vs 120cyc of MFMA with only 2 waves/SIMD to overlap).
// Costs ~48 VGPR (60 -> ~110-130); no launch_bounds min-wave (r1 lesson).
__global__ __launch_bounds__(256) void gemm_mfma(
    const unsigned short* __restrict__ Ahi, const unsigned short* __restrict__ Alo,
    const unsigned short* __restrict__ Bhi, const unsigned short* __restrict__ Blo,
    float* __restrict__ Cbase, size_t Cstride, int N, int K, int Nt, int kchunk)
{
    int tid = threadIdx.x;
    int w = tid >> 6, l = tid & 63;
    int bid = blockIdx.x;
    int nt = bid % Nt, mt = bid / Nt;
    int m0 = mt << 6, n0 = nt << 7;
    int kbeg = blockIdx.z * kchunk;
    int kend = kbeg + kchunk;
    if (kend > K) kend = K;
    int steps = (kend - kbeg) >> 5;
    float* C = Cbase + (size_t)blockIdx.z * Cstride;

    int wm = (w & 1) << 5;          // wave row offset within block: 0/32
    int wn = (w >> 1) << 6;         // wave col offset within block: 0/64
    int lr = l & 15;
    int lk = (l >> 4) << 3;

    size_t aoff = (size_t)(m0 + wm + lr) * K + kbeg + lk;
    size_t boff = (size_t)(n0 + wn + lr) * K + kbeg + lk;
    const unsigned short* pah = Ahi + aoff;
    const unsigned short* pal = Alo + aoff;
    const unsigned short* pbh = Bhi + boff;
    const unsigned short* pbl = Blo + boff;
    const size_t rstr = (size_t)16 * K;   // subtile stride (16 rows/cols)

    f32x4 acc[2][4];
#pragma unroll
    for (int i = 0; i < 2; i++)
#pragma unroll
        for (int j = 0; j < 4; j++) acc[i][j] = (f32x4){0.f, 0.f, 0.f, 0.f};

    // current-step fragments
    bf16x8 ah0 = *(const bf16x8*)(pah);
    bf16x8 ah1 = *(const bf16x8*)(pah + rstr);
    bf16x8 al0 = *(const bf16x8*)(pal);
    bf16x8 al1 = *(const bf16x8*)(pal + rstr);
    bf16x8 bh[4], bl[4];
#pragma unroll
    for (int c = 0; c < 4; c++) {
        bh[c] = *(const bf16x8*)(pbh + (size_t)c * rstr);
        bl[c] = *(const bf16x8*)(pbl + (size_t)c * rstr);
    }

    for (int s = 0; s < steps; s++) {
        bool more = (s + 1 < steps);
        bf16x8 nah0, nah1, nal0, nal1, nbh[4], nbl[4];
        if (more) {
            int ko = (s + 1) << 5;
            nah0 = *(const bf16x8*)(pah + ko);
            nah1 = *(const bf16x8*)(pah + rstr + ko);
            nal0 = *(const bf16x8*)(pal + ko);
            nal1 = *(const bf16x8*)(pal + rstr + ko);
#pragma unroll
            for (int c = 0; c < 4; c++) {
                nbh[c] = *(const bf16x8*)(pbh + (size_t)c * rstr + ko);
                nbl[c] = *(const bf16x8*)(pbl + (size_t)c * rstr + ko);
            }
        }
        // pass 1: alo*bhi
#pragma unroll
        for (int c = 0; c < 4; c++) {
            acc[0][c] = __builtin_amdgcn_mfma_f32_16x16x32_bf16(al0, bh[c], acc[0][c], 0, 0, 0);
            acc[1][c] = __builtin_amdgcn_mfma_f32_16x16x32_bf16(al1, bh[c], acc[1][c], 0, 0, 0);
        }
        // pass 2: ahi*blo
#pragma unroll
        for (int c = 0; c < 4; c++) {
            acc[0][c] = __builtin_amdgcn_mfma_f32_16x16x32_bf16(ah0, bl[c], acc[0][c], 0, 0, 0);
            acc[1][c] = __builtin_amdgcn_mfma_f32_16x16x32_bf16(ah1, bl[c], acc[1][c], 0, 0, 0);
        }
        // pass 3: ahi*bhi
#pragma unroll
        for (int c = 0; c < 4; c++) {
            acc[0][c] = __builtin_amdgcn_mfma_f32_16x16x32_bf16(ah0, bh[c], acc[0][c], 0, 0, 0);
            acc[1][c] = __builtin_amdgcn_mfma_f32_16x16x32_bf16(ah1, bh[c], acc[1][c], 0, 0, 0);
        }
        if (more) {
            ah0 = nah0; ah1 = nah1; al0 = nal0; al1 = nal1;
#pragma unroll
            for (int c = 0; c < 4; c++) { bh[c] = nbh[c]; bl[c] = nbl[c]; }
        }
    }

    int rrow = (l >> 4) << 2;
#pragma unroll
    for (int ri = 0; ri < 2; ri++) {
#pragma unroll
        for (int ci = 0; ci < 4; ci++) {
            int row = m0 + wm + (ri << 4) + rrow;
            int col = n0 + wn + (ci << 4) + lr;
            float* cp = C + (size_t)row * N + col;
#pragma unroll
            for (int r = 0; r < 4; r++) cp[(size_t)r * N] = acc[ri][ci][r];
        }
    }
}

// out[i] = relu(bias[i%1024] + sum_z p[i + z*stride]) over 1048576 elements
__global__ __launch_bounds__(256) void bias_relu_sum(const float* __restrict__ p,
    size_t stride, int nz, const float* __restrict__ b, float* __restrict__ out)
{
    int i = blockIdx.x * 256 + threadIdx.x;
    float v = b[i & 1023];
    for (int z = 0; z < nz; z++) v += p[i + (size_t)z * stride];
    out[i] = v > 0.f ? v : 0.f;
}

// one LSTM step for one layer. 512 blocks = 512 unit-pairs; register-tiled
// (4 batches x 1 unit x 4 gates per thread); h tile XOR bank-swizzled.
__global__ __launch_bounds__(256) void lstm_step(
    const float* __restrict__ gx,      // [1024][4096] rows t*32+b
    const float* __restrict__ whh,     // [4096][1024]
    const float* __restrict__ bsum,    // [4096] (caller offsets for layer)
    const float* __restrict__ hprev,   // rows b*1024 (pre-offset for t/layer)
    const float* __restrict__ cprev,   // idx b*1024+j (pre-offset for layer)
    float* __restrict__ cout,          // idx b*1024+j
    float* __restrict__ Hout,          // rows t*32+b
    const unsigned char* __restrict__ dmask, // &done[t*32]
    int t)
{
    __shared__ float Hs[32][132];      // h chunk: 32 batches x 128 cols (swizzled)
    __shared__ float Ws[8][132];       // w chunk: 2 units x 4 gates x 128 cols
    __shared__ float4 part[16][65];    // k-slice partials, odd stride
    int tid = threadIdx.x;
    int bg = tid & 7;
    int u  = (tid >> 3) & 1;
    int s  = tid >> 4;
    int jb = (int)blockIdx.x << 1;
    int r0 = tid >> 5;
    int c40 = tid & 31;

    float nds[4];
#pragma unroll
    for (int rep = 0; rep < 4; rep++) nds[rep] = dmask[r0 + (rep << 3)] ? 0.f : 1.f;

    int wuu = tid >> 7, wg = (tid >> 5) & 3, wc = tid & 31;
    const float* wsrc = whh + ((size_t)(wg << 10) + jb + wuu) * 1024 + (wc << 2);

    float acc[4][4];
#pragma unroll
    for (int i = 0; i < 4; i++)
#pragma unroll
        for (int g = 0; g < 4; g++) acc[i][g] = 0.f;

    for (int kt = 0; kt < 8; kt++) {
        if (kt) __syncthreads();
#pragma unroll
        for (int rep = 0; rep < 4; rep++) {
            int r = r0 + (rep << 3);
            float4 h4 = *(const float4*)(hprev + (size_t)r * 1024 + (kt << 7) + (c40 << 2));
            float nd = nds[rep];
            h4.x *= nd; h4.y *= nd; h4.z *= nd; h4.w *= nd;
            *(float4*)&Hs[r][(c40 ^ ((r >> 2) & 7)) << 2] = h4;
        }
        *(float4*)&Ws[(wuu << 2) + wg][wc << 2] = *(const float4*)(wsrc + (kt << 7));
        __syncthreads();
#pragma unroll
        for (int kq = 0; kq < 2; kq++) {
            int col4 = (s << 1) + kq;
            float4 w0 = *(const float4*)&Ws[(u << 2) + 0][col4 << 2];
            float4 w1 = *(const float4*)&Ws[(u << 2) + 1][col4 << 2];
            float4 w2 = *(const float4*)&Ws[(u << 2) + 2][col4 << 2];
            float4 w3 = *(const float4*)&Ws[(u << 2) + 3][col4 << 2];
#pragma unroll
            for (int i = 0; i < 4; i++) {
                float4 h4 = *(const float4*)&Hs[(bg << 2) + i][(col4 ^ bg) << 2];
                acc[i][0] = fmaf(h4.x, w0.x, fmaf(h4.y, w0.y, fmaf(h4.z, w0.z, fmaf(h4.w, w0.w, acc[i][0]))));
                acc[i][1] = fmaf(h4.x, w1.x, fmaf(h4.y, w1.y, fmaf(h4.z, w1.z, fmaf(h4.w, w1.w, acc[i][1]))));
                acc[i][2] = fmaf(h4.x, w2.x, fmaf(h4.y, w2.y, fmaf(h4.z, w2.z, fmaf(h4.w, w2.w, acc[i][2]))));
                acc[i][3] = fmaf(h4.x, w3.x, fmaf(h4.y, w3.y, fmaf(h4.z, w3.z, fmaf(h4.w, w3.w, acc[i][3]))));
            }
        }
    }

#pragma unroll
    for (int i = 0; i < 4; i++) {
        float4 pv; pv.x = acc[i][0]; pv.y = acc[i][1]; pv.z = acc[i][2]; pv.w = acc[i][3];
        part[s][(((bg << 2) + i) << 1) + u] = pv;
    }
    __syncthreads();
    if (tid < 64) {
        int b = tid & 31, uu = tid >> 5;
        float4 sum; sum.x = 0.f; sum.y = 0.f; sum.z = 0.f; sum.w = 0.f;
#pragma unroll
        for (int sl = 0; sl < 16; sl++) {
            float4 pv = part[sl][(b << 1) + uu];
            sum.x += pv.x; sum.y += pv.y; sum.z += pv.z; sum.w += pv.w;
        }
        int j = jb + uu;
        int row = (t << 5) + b;
        const float* gp = gx + (size_t)row * 4096 + j;
        float g0 = sum.x + gp[0]    + bsum[j];
        float g1 = sum.y + gp[1024] + bsum[j + 1024];
        float g2 = sum.z + gp[2048] + bsum[j + 2048];
        float g3 = sum.w + gp[3072] + bsum[j + 3072];
        float nd = dmask[b] ? 0.f : 1.f;
        float cp = cprev[(size_t)b * 1024 + j] * nd;
        float si = 1.f / (1.f + expf(-g0));
        float sf = 1.f / (1.f + expf(-g1));
        float so = 1.f / (1.f + expf(-g3));
        float cn = sf * cp + si * tanhf(g2);
        float hn = so * tanhf(cn);
        cout[(size_t)b * 1024 + j] = cn;
        Hout[(size_t)row * 1024 + j] = hn;
    }
}

__global__ __launch_bounds__(256) void heads_k(const float* __restrict__ Hc,
    const float* __restrict__ pw, const float* __restrict__ pb,
    const float* __restrict__ bw, const float* __restrict__ bbias,
    float* __restrict__ out)
{
    __shared__ float red[8][264];
    int n = blockIdx.x, tid = threadIdx.x;
    float4 x4 = *(const float4*)(Hc + (size_t)n * 1024 + (tid << 2));
#pragma unroll
    for (int a = 0; a < 7; a++) {
        float4 w4 = *(const float4*)(pw + (size_t)a * 1024 + (tid << 2));
        red[a][tid] = x4.x * w4.x + x4.y * w4.y + x4.z * w4.z + x4.w * w4.w;
    }
    {
        float4 w4 = *(const float4*)(bw + (tid << 2));
        red[7][tid] = x4.x * w4.x + x4.y * w4.y + x4.z * w4.z + x4.w * w4.w;
    }
    __syncthreads();
    for (int off = 128; off > 0; off >>= 1) {
        if (tid < off) {
#pragma unroll
            for (int a = 0; a < 8; a++) red[a][tid] += red[a][tid + off];
        }
        __syncthreads();
    }
    if (tid == 0) {
        float best = -1e30f; int bi = 0;
        for (int a = 0; a < 7; a++) {
            float L = red[a][0] + pb[a];
            out[n * 7 + a] = L;
            if (L > best) { best = L; bi = a; }
        }
        out[7168 + n] = red[7][0] + bbias[0];
        out[8192 + n] = (float)bi;
    }
}

__global__ __launch_bounds__(256) void final_copy(const float* __restrict__ H0,
    const float* __restrict__ H1, const float* __restrict__ cst, float* __restrict__ out)
{
    int i = blockIdx.x * 256 + threadIdx.x;   // 131072 exact
    if (i < 65536) {
        int l = i >> 15;
        int rem = i & 32767;
        const float* H = l ? H1 : H0;
        out[9216 + i] = H[(size_t)(31 * 32) * 1024 + rem];
    } else {
        out[74752 + (i - 65536)] = cst[i - 65536];
    }
}

extern "C" void kernel_launch(void* const* d_in, const int* in_sizes, int n_in,
                              void* d_out, int out_size, void* d_ws, size_t ws_size,
                              hipStream_t stream)
{
    (void)in_sizes; (void)n_in; (void)out_size; (void)ws_size;
    const float* frame = (const float*)d_in[0];
    const unsigned char* done8 = (const unsigned char*)d_in[1];
    const float* h0   = (const float*)d_in[2];
    const float* c0   = (const float*)d_in[3];
    const float* cw1  = (const float*)d_in[4];
    const float* cb1  = (const float*)d_in[5];
    const float* cw2  = (const float*)d_in[6];
    const float* cb2  = (const float*)d_in[7];
    const float* cw3  = (const float*)d_in[8];
    const float* cb3  = (const float*)d_in[9];
    const float* fw1  = (const float*)d_in[10];
    const float* fb1  = (const float*)d_in[11];
    const float* fw2  = (const float*)d_in[12];
    const float* fb2  = (const float*)d_in[13];
    const float* wih0 = (const float*)d_in[14];
    const float* whh0 = (const float*)d_in[15];
    const float* bih0 = (const float*)d_in[16];
    const float* bhh0 = (const float*)d_in[17];
    const float* wih1 = (const float*)d_in[18];
    const float* whh1 = (const float*)d_in[19];
    const float* bih1 = (const float*)d_in[20];
    const float* bhh1 = (const float*)d_in[21];
    const float* pw   = (const float*)d_in[22];
    const float* pb   = (const float*)d_in[23];
    const float* bw   = (const float*)d_in[24];
    const float* bbias= (const float*)d_in[25];

    float* ws   = (float*)d_ws;
    float* A    = ws;                      // 14,450,688
    float* Bv   = A + 14450688;            //  7,225,344
    float* fc1  = Bv + 7225344;            //  1,048,576
    float* cin  = fc1 + 1048576;           //  1,048,576
    float* H0   = cin + 1048576;           //  1,048,576
    float* H1   = H0 + 1048576;            //  1,048,576
    float* cst  = H1 + 1048576;            //     65,536
    float* bsum = cst + 65536;             //      8,192
    float* wt   = bsum + 8192;             //     19,296
    float* conv2f = A;
    float* conv3o = Bv;                    // [1024][3872] fp32
    // FC1 operands (bf16 planes; conv2f dead after conv3)
    unsigned short* c3hi = (unsigned short*)(A);
    unsigned short* c3lo = (unsigned short*)(A + 1982464);
    unsigned short* f1hi = (unsigned short*)(A + 3964928);
    unsigned short* f1lo = (unsigned short*)(A + 5947392);
    float* fc1p = Bv;                      // FC1 partials 6x1,048,576 (conv3o dead)
    // FC2 operands (FC1 partials dead after relu)
    unsigned short* fc1hi = (unsigned short*)(Bv);
    unsigned short* fc1lo = (unsigned short*)(Bv + 524288);
    unsigned short* fw2hi = (unsigned short*)(Bv + 1048576);
    unsigned short* fw2lo = (unsigned short*)(Bv + 1572864);
    float* fc2p = A;                       // FC2 partials 4x1,048,576 (c3/f1 dead)
    // gx phase (FC2 partials dead after relu)
    unsigned short* cinhi = (unsigned short*)(Bv + 2097152);
    unsigned short* cinlo = (unsigned short*)(Bv + 2621440);
    unsigned short* h0hi  = (unsigned short*)(Bv + 3145728);
    unsigned short* h0lo  = (unsigned short*)(Bv + 3670016);
    unsigned short* w0hi = (unsigned short*)(A);
    unsigned short* w0lo = (unsigned short*)(A + 2097152);
    unsigned short* w1hi = (unsigned short*)(A + 4194304);
    unsigned short* w1lo = (unsigned short*)(A + 6291456);
    float* gx = A + 8388608;               // [1024][4096] fp32, ends 12,582,912
    float* out = (float*)d_out;

    repack_w<<<76, 256, 0, stream>>>(cw1, cw2, cw3, wt);
    bsum_k<<<32, 256, 0, stream>>>(bih0, bhh0, bih1, bhh1, bsum);

    for (int ch = 0; ch < 8; ch++) {
        conv1_k<<<1764, 256, 0, stream>>>(frame, wt, cb1, Bv, ch * 128);
        convg_k<42, 21><<<441, 256, 0, stream>>>(Bv, wt + 864, cb2, conv2f, ch * 128 * 441);
    }
    convg_k<21, 11><<<968, 256, 0, stream>>>(conv2f, wt + 10080, cb3, conv3o, 0);

    // convert conv3o -> bf16 planes; repack fw1 -> bf16 planes
    cvt_split<<<1936, 256, 0, stream>>>(conv3o, c3hi, c3lo, 3964928);
    repack_fw1<<<1024, 256, 0, stream>>>(fw1, f1hi, f1lo);

    // FC1: M=1024 N=1024 K=3872, tile 64x128 -> Mt=16,Nt=8 (128 blocks), splitk6
    { dim3 g(128, 1, 6); gemm_mfma<<<g, 256, 0, stream>>>(c3hi, c3lo, f1hi, f1lo,
        fc1p, 1048576, 1024, 3872, 8, 672); }
    bias_relu_sum<<<4096, 256, 0, stream>>>(fc1p, 1048576, 6, fb1, fc1);

    // FC2: K=1024, splitk4
    cvt_split<<<512, 256, 0, stream>>>(fc1, fc1hi, fc1lo, 1048576);
    cvt_split<<<512, 256, 0, stream>>>(fw2, fw2hi, fw2lo, 1048576);
    { dim3 g(128, 1, 4); gemm_mfma<<<g, 256, 0, stream>>>(fc1hi, fc1lo, fw2hi, fw2lo,
        fc2p, 1048576, 1024, 1024, 8, 256); }
    bias_relu_sum<<<4096, 256, 0, stream>>>(fc2p, 1048576, 4, fb2, cin);

    // gx0: M=1024 N=4096 K=1024, Mt=16,Nt=32 -> 512 blocks, no splitk
    cvt_split<<<512, 256, 0, stream>>>(cin, cinhi, cinlo, 1048576);
    cvt_split<<<2048, 256, 0, stream>>>(wih0, w0hi, w0lo, 4194304);
    cvt_split<<<2048, 256, 0, stream>>>(wih1, w1hi, w1lo, 4194304);
    { dim3 g(512, 1, 1); gemm_mfma<<<g, 256, 0, stream>>>(cinhi, cinlo, w0hi, w0lo,
        gx, 0, 4096, 1024, 32, 1024); }
    for (int t = 0; t < 32; t++) {
        const float* hp = t ? (H0 + (size_t)(t - 1) * 32768) : h0;
        const float* cp = t ? cst : c0;
        lstm_step<<<512, 256, 0, stream>>>(gx, whh0, bsum, hp, cp, cst, H0, done8 + t * 32, t);
    }
    // gx1: A = H0 (bf16), B = wih1 (bf16), overwrite gx
    cvt_split<<<512, 256, 0, stream>>>(H0, h0hi, h0lo, 1048576);
    { dim3 g(512, 1, 1); gemm_mfma<<<g, 256, 0, stream>>>(h0hi, h0lo, w1hi, w1lo,
        gx, 0, 4096, 1024, 32, 1024); }
    for (int t = 0; t < 32; t++) {
        const float* hp = t ? (H1 + (size_t)(t - 1) * 32768) : (h0 + 32768);
        const float* cp = t ? (cst + 32768) : (c0 + 32768);
        lstm_step<<<512, 256, 0, stream>>>(gx, whh1, bsum + 4096, hp, cp, cst + 32768, H1, done8 + t * 32, t);
    }
    heads_k<<<1024, 256, 0, stream>>>(H1, pw, pb, bw, bbias, out);
    final_copy<<<512, 256, 0, stream>>>(H0, H1, cst, out);
}